// Round 2
// baseline (738.291 us; speedup 1.0000x reference)
//
#include <hip/hip_runtime.h>
#include <hip/hip_bf16.h>

#define DEVB 64
#define LSEQ 512
#define DDIM 600

typedef short short8 __attribute__((ext_vector_type(8)));
typedef float f32x4 __attribute__((ext_vector_type(4)));

constexpr int LDP = 40;   // padded LDS row stride (bf16 elems): 80 B = 20 dwords -> 2-way max conflict

__device__ __forceinline__ unsigned short f2bf(float x) {
    union { float f; unsigned u; } v; v.f = x;
    unsigned r = v.u + 0x7fffu + ((v.u >> 16) & 1u);   // RNE
    return (unsigned short)(r >> 16);
}
__device__ __forceinline__ float bf2f(unsigned short h) {
    union { unsigned u; float f; } v; v.u = ((unsigned)h) << 16; return v.f;
}
__device__ __forceinline__ void cvt_hilo(float x, unsigned short& hi, unsigned short& lo) {
    hi = f2bf(x);
    lo = f2bf(x - bf2f(hi));
}
__device__ __forceinline__ f32x4 mfma16(short8 a, short8 b, f32x4 c) {
    return __builtin_amdgcn_mfma_f32_16x16x32_bf16(a, b, c, 0, 0, 0);
}

// ---------------------------------------------------------------------------
// K1: attn[b][p][h] = sum_d P[b][p][d] * H[b][h][d]   (fp32 out, hi/lo bf16 MFMA)
// ---------------------------------------------------------------------------
__global__ __launch_bounds__(256) void attn_gemm(
    const float* __restrict__ P, const float* __restrict__ H,
    float* __restrict__ attn)
{
    const int blk = blockIdx.x;
    const int b  = blk >> 4;
    const int pt = ((blk >> 2) & 3) << 7;
    const int ht = (blk & 3) << 7;
    const float* Pb = P + (size_t)b * LSEQ * DDIM;
    const float* Hb = H + (size_t)b * LSEQ * DDIM;
    float* Ab = attn + (size_t)b * LSEQ * LSEQ;

    __shared__ unsigned short Ahi[128 * LDP], Alo[128 * LDP];
    __shared__ unsigned short Bhi[128 * LDP], Blo[128 * LDP];

    const int t    = threadIdx.x;
    const int lane = t & 63;
    const int wave = t >> 6;
    const int wm = (wave >> 1) << 6;
    const int wn = (wave & 1) << 6;
    const int fr = lane & 15;
    const int fq = lane >> 4;

    f32x4 acc[4][4];
#pragma unroll
    for (int i = 0; i < 4; ++i)
#pragma unroll
        for (int j = 0; j < 4; ++j) acc[i][j] = (f32x4){0.f, 0.f, 0.f, 0.f};

    for (int k0 = 0; k0 < DDIM; k0 += 32) {
        const bool full = (k0 + 32 <= DDIM);
#pragma unroll
        for (int r = 0; r < 4; ++r) {
            int idx = t + (r << 8);
            int row = idx >> 3;
            int c4  = (idx & 7) << 2;
            // A tile (P)
            {
                const float* src = Pb + (size_t)(pt + row) * DDIM + k0 + c4;
                float x0, x1, x2, x3;
                if (full) { float4 v = *(const float4*)src; x0 = v.x; x1 = v.y; x2 = v.z; x3 = v.w; }
                else {
                    x0 = (k0 + c4 + 0 < DDIM) ? src[0] : 0.f;
                    x1 = (k0 + c4 + 1 < DDIM) ? src[1] : 0.f;
                    x2 = (k0 + c4 + 2 < DDIM) ? src[2] : 0.f;
                    x3 = (k0 + c4 + 3 < DDIM) ? src[3] : 0.f;
                }
                ushort4 hi, lo;
                cvt_hilo(x0, hi.x, lo.x);
                cvt_hilo(x1, hi.y, lo.y);
                cvt_hilo(x2, hi.z, lo.z);
                cvt_hilo(x3, hi.w, lo.w);
                *(ushort4*)&Ahi[row * LDP + c4] = hi;
                *(ushort4*)&Alo[row * LDP + c4] = lo;
            }
            // B tile (H)
            {
                const float* src = Hb + (size_t)(ht + row) * DDIM + k0 + c4;
                float x0, x1, x2, x3;
                if (full) { float4 v = *(const float4*)src; x0 = v.x; x1 = v.y; x2 = v.z; x3 = v.w; }
                else {
                    x0 = (k0 + c4 + 0 < DDIM) ? src[0] : 0.f;
                    x1 = (k0 + c4 + 1 < DDIM) ? src[1] : 0.f;
                    x2 = (k0 + c4 + 2 < DDIM) ? src[2] : 0.f;
                    x3 = (k0 + c4 + 3 < DDIM) ? src[3] : 0.f;
                }
                ushort4 hi, lo;
                cvt_hilo(x0, hi.x, lo.x);
                cvt_hilo(x1, hi.y, lo.y);
                cvt_hilo(x2, hi.z, lo.z);
                cvt_hilo(x3, hi.w, lo.w);
                *(ushort4*)&Bhi[row * LDP + c4] = hi;
                *(ushort4*)&Blo[row * LDP + c4] = lo;
            }
        }
        __syncthreads();

        short8 ah[4], al[4], bh[4], bl[4];
#pragma unroll
        for (int i = 0; i < 4; ++i) {
            ah[i] = *(const short8*)&Ahi[(wm + (i << 4) + fr) * LDP + (fq << 3)];
            al[i] = *(const short8*)&Alo[(wm + (i << 4) + fr) * LDP + (fq << 3)];
            bh[i] = *(const short8*)&Bhi[(wn + (i << 4) + fr) * LDP + (fq << 3)];
            bl[i] = *(const short8*)&Blo[(wn + (i << 4) + fr) * LDP + (fq << 3)];
        }
#pragma unroll
        for (int mi = 0; mi < 4; ++mi)
#pragma unroll
            for (int ni = 0; ni < 4; ++ni) {
                f32x4 c = acc[mi][ni];
                c = mfma16(ah[mi], bh[ni], c);
                c = mfma16(ah[mi], bl[ni], c);
                c = mfma16(al[mi], bh[ni], c);
                acc[mi][ni] = c;
            }
        __syncthreads();
    }

#pragma unroll
    for (int mi = 0; mi < 4; ++mi)
#pragma unroll
        for (int ni = 0; ni < 4; ++ni)
#pragma unroll
            for (int j = 0; j < 4; ++j) {
                int p = pt + wm + (mi << 4) + (fq << 2) + j;
                int h = ht + wn + (ni << 4) + fr;
                Ab[(size_t)p * LSEQ + h] = acc[mi][ni][j];
            }
}

// ---------------------------------------------------------------------------
// K2: per (b,p) row stats over h:  M = max(s*m), R = 1/(T + EPS*S)
// ---------------------------------------------------------------------------
__global__ __launch_bounds__(256) void row_stats(
    const float* __restrict__ attn, const float* __restrict__ hmask,
    float* __restrict__ M1, float* __restrict__ R1)
{
    int rowid = (blockIdx.x << 2) + (threadIdx.x >> 6);
    int lane  = threadIdx.x & 63;
    int b     = rowid >> 9;
    const float* row = attn + (size_t)rowid * LSEQ;
    const float* hm  = hmask + (b << 9);

    float4 s0 = *(const float4*)(row + (lane << 3));
    float4 s1 = *(const float4*)(row + (lane << 3) + 4);
    float4 m0 = *(const float4*)(hm + (lane << 3));
    float4 m1 = *(const float4*)(hm + (lane << 3) + 4);

    float v[8], mk[8];
    v[0] = s0.x * m0.x; mk[0] = m0.x;
    v[1] = s0.y * m0.y; mk[1] = m0.y;
    v[2] = s0.z * m0.z; mk[2] = m0.z;
    v[3] = s0.w * m0.w; mk[3] = m0.w;
    v[4] = s1.x * m1.x; mk[4] = m1.x;
    v[5] = s1.y * m1.y; mk[5] = m1.y;
    v[6] = s1.z * m1.z; mk[6] = m1.z;
    v[7] = s1.w * m1.w; mk[7] = m1.w;

    float mx = -1e30f;
#pragma unroll
    for (int i = 0; i < 8; ++i) mx = fmaxf(mx, v[i]);
#pragma unroll
    for (int off = 32; off; off >>= 1) mx = fmaxf(mx, __shfl_xor(mx, off));

    float T = 0.f, S = 0.f;
#pragma unroll
    for (int i = 0; i < 8; ++i) {
        float e = __expf(v[i] - mx);
        S += e;
        T += mk[i] * e;
    }
#pragma unroll
    for (int off = 32; off; off >>= 1) { T += __shfl_xor(T, off); S += __shfl_xor(S, off); }

    if (lane == 0) {
        M1[rowid] = mx;
        R1[rowid] = 1.f / (T + 1e-13f * S);
    }
}

// ---------------------------------------------------------------------------
// K3: per (b,h) column stats over p (online masked softmax stats)
// ---------------------------------------------------------------------------
__global__ __launch_bounds__(256) void col_stats(
    const float* __restrict__ attn, const float* __restrict__ pmask,
    float* __restrict__ M2, float* __restrict__ R2)
{
    int b  = blockIdx.x >> 3;
    int h0 = (blockIdx.x & 7) << 6;
    int lane = threadIdx.x & 63;
    int wave = threadIdx.x >> 6;
    int h = h0 + lane;
    const float* Ab = attn + (size_t)b * LSEQ * LSEQ;
    const float* pm = pmask + (b << 9);

    float mx[4] = {-1e30f, -1e30f, -1e30f, -1e30f};
    float T[4]  = {0.f, 0.f, 0.f, 0.f};
    float S[4]  = {0.f, 0.f, 0.f, 0.f};

    for (int p = wave << 7; p < (wave << 7) + 128; p += 4) {
#pragma unroll
        for (int j = 0; j < 4; ++j) {
            float s = Ab[(size_t)(p + j) * LSEQ + h];
            float m = pm[p + j];
            float v = s * m;
            float nm = fmaxf(mx[j], v);
            float sc = __expf(mx[j] - nm);
            float e  = __expf(v - nm);
            T[j] = T[j] * sc + m * e;
            S[j] = S[j] * sc + e;
            mx[j] = nm;
        }
    }
    float gm = fmaxf(fmaxf(mx[0], mx[1]), fmaxf(mx[2], mx[3]));
    float gT = 0.f, gS = 0.f;
#pragma unroll
    for (int j = 0; j < 4; ++j) {
        float sc = __expf(mx[j] - gm);
        gT += T[j] * sc;
        gS += S[j] * sc;
    }

    __shared__ float sM[4][64], sT[4][64], sS[4][64];
    sM[wave][lane] = gm; sT[wave][lane] = gT; sS[wave][lane] = gS;
    __syncthreads();
    if (wave == 0) {
        float fm = sM[0][lane];
#pragma unroll
        for (int w = 1; w < 4; ++w) fm = fmaxf(fm, sM[w][lane]);
        float fT = 0.f, fS = 0.f;
#pragma unroll
        for (int w = 0; w < 4; ++w) {
            float sc = __expf(sM[w][lane] - fm);
            fT += sT[w][lane] * sc;
            fS += sS[w][lane] * sc;
        }
        M2[(b << 9) + h] = fm;
        R2[(b << 9) + h] = 1.f / (fT + 1e-13f * fS);
    }
}

// ---------------------------------------------------------------------------
// K4/K5: out[b][m][d] = mask_m[m] * sum_k w(m,k) * Bsrc[b][k][d]
//   w(m,k) = mask_k[k] ? exp(attnval - M[m]) * R[m] : 0
//   TRANSA=0: attnval = attn[b][m][k]   (weighted premise,  k = h, Bsrc = H)
//   TRANSA=1: attnval = attn[b][k][m]   (weighted hypothesis, k = p, Bsrc = P)
// ---------------------------------------------------------------------------
template <int TRANSA>
__global__ __launch_bounds__(256) void wsum(
    const float* __restrict__ attn, const float* __restrict__ Bsrc,
    const float* __restrict__ mask_k, const float* __restrict__ mask_m,
    const float* __restrict__ Mst, const float* __restrict__ Rst,
    float* __restrict__ out)
{
    const int blk = blockIdx.x;
    const int b   = blk / 20;
    const int rem = blk % 20;
    const int m0  = (rem / 5) << 7;
    const int n0  = (rem % 5) << 7;

    const float* Ab  = attn + (size_t)b * LSEQ * LSEQ;
    const float* Bb  = Bsrc + (size_t)b * LSEQ * DDIM;
    const float* mkb = mask_k + (b << 9);

    __shared__ unsigned short Wl[128 * LDP];
    __shared__ unsigned short Bl[128 * LDP];
    __shared__ float Ml[128], Rl[128], Mm[128];

    const int t    = threadIdx.x;
    const int lane = t & 63;
    const int wave = t >> 6;
    const int wm = (wave >> 1) << 6;
    const int wn = (wave & 1) << 6;
    const int fr = lane & 15;
    const int fq = lane >> 4;

    if (t < 128) {
        Ml[t] = Mst[(b << 9) + m0 + t];
        Rl[t] = Rst[(b << 9) + m0 + t];
        Mm[t] = mask_m[(b << 9) + m0 + t];
    }
    __syncthreads();

    f32x4 acc[4][4];
#pragma unroll
    for (int i = 0; i < 4; ++i)
#pragma unroll
        for (int j = 0; j < 4; ++j) acc[i][j] = (f32x4){0.f, 0.f, 0.f, 0.f};

    for (int k0 = 0; k0 < LSEQ; k0 += 32) {
        // ---- A tile: softmax weights -> bf16, LDS layout [m][k]
        if constexpr (TRANSA == 0) {
#pragma unroll
            for (int r = 0; r < 4; ++r) {
                int idx = t + (r << 8);
                int row = idx >> 3;
                int c4  = (idx & 7) << 2;
                float4 x  = *(const float4*)(Ab + (size_t)(m0 + row) * LSEQ + k0 + c4);
                float4 km = *(const float4*)(mkb + k0 + c4);
                float Mv = Ml[row], Rv = Rl[row];
                ushort4 w;
                w.x = (km.x != 0.f) ? f2bf(__expf(x.x - Mv) * Rv) : (unsigned short)0;
                w.y = (km.y != 0.f) ? f2bf(__expf(x.y - Mv) * Rv) : (unsigned short)0;
                w.z = (km.z != 0.f) ? f2bf(__expf(x.z - Mv) * Rv) : (unsigned short)0;
                w.w = (km.w != 0.f) ? f2bf(__expf(x.w - Mv) * Rv) : (unsigned short)0;
                *(ushort4*)&Wl[row * LDP + c4] = w;
            }
        } else {
#pragma unroll
            for (int r = 0; r < 4; ++r) {
                int mh = t & 127;
                int pq = (t >> 7) + (r << 1);
                float Mv = Ml[mh], Rv = Rl[mh];
                ushort4 w;
#pragma unroll
                for (int j = 0; j < 4; ++j) {
                    int k = k0 + (pq << 2) + j;
                    float x  = Ab[(size_t)k * LSEQ + m0 + mh];
                    float km = mkb[k];
                    ((unsigned short*)&w)[j] =
                        (km != 0.f) ? f2bf(__expf(x - Mv) * Rv) : (unsigned short)0;
                }
                *(ushort4*)&Wl[mh * LDP + (pq << 2)] = w;
            }
        }
        // ---- B tile: Bsrc[k][n] -> LDS layout [n][k] (transposed), bf16
#pragma unroll
        for (int r = 0; r < 4; ++r) {
            int d  = t & 127;
            int kq = (t >> 7) + (r << 1);
            bool valid = (n0 + d) < DDIM;
            ushort4 v;
#pragma unroll
            for (int j = 0; j < 4; ++j) {
                int k = k0 + (kq << 2) + j;
                float x = valid ? Bb[(size_t)k * DDIM + n0 + d] : 0.f;
                ((unsigned short*)&v)[j] = f2bf(x);
            }
            *(ushort4*)&Bl[d * LDP + (kq << 2)] = v;
        }
        __syncthreads();

        short8 af[4], bfr[4];
#pragma unroll
        for (int i = 0; i < 4; ++i) {
            af[i]  = *(const short8*)&Wl[(wm + (i << 4) + fr) * LDP + (fq << 3)];
            bfr[i] = *(const short8*)&Bl[(wn + (i << 4) + fr) * LDP + (fq << 3)];
        }
#pragma unroll
        for (int mi = 0; mi < 4; ++mi)
#pragma unroll
            for (int ni = 0; ni < 4; ++ni)
                acc[mi][ni] = mfma16(af[mi], bfr[ni], acc[mi][ni]);
        __syncthreads();
    }

#pragma unroll
    for (int mi = 0; mi < 4; ++mi)
#pragma unroll
        for (int j = 0; j < 4; ++j) {
            int row = wm + (mi << 4) + (fq << 2) + j;
            float mm = Mm[row];
#pragma unroll
            for (int ni = 0; ni < 4; ++ni) {
                int d = n0 + wn + (ni << 4) + fr;
                if (d < DDIM)
                    out[((size_t)(b << 9) + m0 + row) * DDIM + d] = mm * acc[mi][ni][j];
            }
        }
}

// ---------------------------------------------------------------------------
extern "C" void kernel_launch(void* const* d_in, const int* in_sizes, int n_in,
                              void* d_out, int out_size, void* d_ws, size_t ws_size,
                              hipStream_t stream)
{
    const float* P  = (const float*)d_in[0];   // encoded_premise   [64,512,600]
    const float* pm = (const float*)d_in[1];   // premise_mask      [64,512]
    const float* H  = (const float*)d_in[2];   // encoded_hypothesis[64,512,600]
    const float* hm = (const float*)d_in[3];   // hypothesis_mask   [64,512]
    float* out = (float*)d_out;

    float* attn = (float*)d_ws;                       // 64*512*512 fp32 = 64 MiB
    float* M1 = attn + (size_t)DEVB * LSEQ * LSEQ;
    float* R1 = M1 + DEVB * LSEQ;
    float* M2 = R1 + DEVB * LSEQ;
    float* R2 = M2 + DEVB * LSEQ;

    attn_gemm<<<DEVB * 16, 256, 0, stream>>>(P, H, attn);
    row_stats<<<DEVB * LSEQ / 4, 256, 0, stream>>>(attn, hm, M1, R1);
    col_stats<<<DEVB * 8, 256, 0, stream>>>(attn, pm, M2, R2);
    wsum<0><<<DEVB * 20, 256, 0, stream>>>(attn, H, hm, pm, M1, R1, out);
    wsum<1><<<DEVB * 20, 256, 0, stream>>>(attn, P, pm, hm, M2, R2,
                                           out + (size_t)DEVB * LSEQ * DDIM);
}

// Round 3
// 482.945 us; speedup vs baseline: 1.5287x; 1.5287x over previous
//
#include <hip/hip_runtime.h>
#include <hip/hip_bf16.h>

#define DEVB 64
#define LSEQ 512
#define DDIM 600

typedef short short8 __attribute__((ext_vector_type(8)));
typedef float f32x4 __attribute__((ext_vector_type(4)));

constexpr int LDP = 40;   // padded LDS row stride (bf16 elems) for GEMM tiles

__device__ __forceinline__ unsigned short f2bf(float x) {
    union { float f; unsigned u; } v; v.f = x;
    unsigned r = v.u + 0x7fffu + ((v.u >> 16) & 1u);   // RNE
    return (unsigned short)(r >> 16);
}
__device__ __forceinline__ float bf2f(unsigned short h) {
    union { unsigned u; float f; } v; v.u = ((unsigned)h) << 16; return v.f;
}
__device__ __forceinline__ void cvt_hilo(float x, unsigned short& hi, unsigned short& lo) {
    hi = f2bf(x);
    lo = f2bf(x - bf2f(hi));
}
__device__ __forceinline__ f32x4 mfma16(short8 a, short8 b, f32x4 c) {
    return __builtin_amdgcn_mfma_f32_16x16x32_bf16(a, b, c, 0, 0, 0);
}

// ---------------------------------------------------------------------------
// K1: attn[b][p][h] = sum_d P[b][p][d] * H[b][h][d]   (fp32 out, hi/lo bf16 MFMA)
// ---------------------------------------------------------------------------
__global__ __launch_bounds__(256) void attn_gemm(
    const float* __restrict__ P, const float* __restrict__ H,
    float* __restrict__ attn)
{
    const int blk = blockIdx.x;
    const int b  = blk >> 4;
    const int pt = ((blk >> 2) & 3) << 7;
    const int ht = (blk & 3) << 7;
    const float* Pb = P + (size_t)b * LSEQ * DDIM;
    const float* Hb = H + (size_t)b * LSEQ * DDIM;
    float* Ab = attn + (size_t)b * LSEQ * LSEQ;

    __shared__ unsigned short Ahi[128 * LDP], Alo[128 * LDP];
    __shared__ unsigned short Bhi[128 * LDP], Blo[128 * LDP];

    const int t    = threadIdx.x;
    const int lane = t & 63;
    const int wave = t >> 6;
    const int wm = (wave >> 1) << 6;
    const int wn = (wave & 1) << 6;
    const int fr = lane & 15;
    const int fq = lane >> 4;

    f32x4 acc[4][4];
#pragma unroll
    for (int i = 0; i < 4; ++i)
#pragma unroll
        for (int j = 0; j < 4; ++j) acc[i][j] = (f32x4){0.f, 0.f, 0.f, 0.f};

    for (int k0 = 0; k0 < DDIM; k0 += 32) {
        const bool full = (k0 + 32 <= DDIM);
#pragma unroll
        for (int r = 0; r < 4; ++r) {
            int idx = t + (r << 8);
            int row = idx >> 3;
            int c4  = (idx & 7) << 2;
            {
                const float* src = Pb + (size_t)(pt + row) * DDIM + k0 + c4;
                float x0, x1, x2, x3;
                if (full) { float4 v = *(const float4*)src; x0 = v.x; x1 = v.y; x2 = v.z; x3 = v.w; }
                else {
                    x0 = (k0 + c4 + 0 < DDIM) ? src[0] : 0.f;
                    x1 = (k0 + c4 + 1 < DDIM) ? src[1] : 0.f;
                    x2 = (k0 + c4 + 2 < DDIM) ? src[2] : 0.f;
                    x3 = (k0 + c4 + 3 < DDIM) ? src[3] : 0.f;
                }
                ushort4 hi, lo;
                cvt_hilo(x0, hi.x, lo.x);
                cvt_hilo(x1, hi.y, lo.y);
                cvt_hilo(x2, hi.z, lo.z);
                cvt_hilo(x3, hi.w, lo.w);
                *(ushort4*)&Ahi[row * LDP + c4] = hi;
                *(ushort4*)&Alo[row * LDP + c4] = lo;
            }
            {
                const float* src = Hb + (size_t)(ht + row) * DDIM + k0 + c4;
                float x0, x1, x2, x3;
                if (full) { float4 v = *(const float4*)src; x0 = v.x; x1 = v.y; x2 = v.z; x3 = v.w; }
                else {
                    x0 = (k0 + c4 + 0 < DDIM) ? src[0] : 0.f;
                    x1 = (k0 + c4 + 1 < DDIM) ? src[1] : 0.f;
                    x2 = (k0 + c4 + 2 < DDIM) ? src[2] : 0.f;
                    x3 = (k0 + c4 + 3 < DDIM) ? src[3] : 0.f;
                }
                ushort4 hi, lo;
                cvt_hilo(x0, hi.x, lo.x);
                cvt_hilo(x1, hi.y, lo.y);
                cvt_hilo(x2, hi.z, lo.z);
                cvt_hilo(x3, hi.w, lo.w);
                *(ushort4*)&Bhi[row * LDP + c4] = hi;
                *(ushort4*)&Blo[row * LDP + c4] = lo;
            }
        }
        __syncthreads();

        short8 ah[4], al[4], bh[4], bl[4];
#pragma unroll
        for (int i = 0; i < 4; ++i) {
            ah[i] = *(const short8*)&Ahi[(wm + (i << 4) + fr) * LDP + (fq << 3)];
            al[i] = *(const short8*)&Alo[(wm + (i << 4) + fr) * LDP + (fq << 3)];
            bh[i] = *(const short8*)&Bhi[(wn + (i << 4) + fr) * LDP + (fq << 3)];
            bl[i] = *(const short8*)&Blo[(wn + (i << 4) + fr) * LDP + (fq << 3)];
        }
#pragma unroll
        for (int mi = 0; mi < 4; ++mi)
#pragma unroll
            for (int ni = 0; ni < 4; ++ni) {
                f32x4 c = acc[mi][ni];
                c = mfma16(ah[mi], bh[ni], c);
                c = mfma16(ah[mi], bl[ni], c);
                c = mfma16(al[mi], bh[ni], c);
                acc[mi][ni] = c;
            }
        __syncthreads();
    }

#pragma unroll
    for (int mi = 0; mi < 4; ++mi)
#pragma unroll
        for (int ni = 0; ni < 4; ++ni)
#pragma unroll
            for (int j = 0; j < 4; ++j) {
                int p = pt + wm + (mi << 4) + (fq << 2) + j;
                int h = ht + wn + (ni << 4) + fr;
                Ab[(size_t)p * LSEQ + h] = acc[mi][ni][j];
            }
}

// ---------------------------------------------------------------------------
// K2: per (b,p) row stats over h: M=max(s*m), R=1/(T+EPS*S); optional W1 bf16
//     W1[b][p][h] = hm[h] * exp(v[h]-M) * R
// ---------------------------------------------------------------------------
__global__ __launch_bounds__(256) void row_stats_w1(
    const float* __restrict__ attn, const float* __restrict__ hmask,
    float* __restrict__ M1, float* __restrict__ R1,
    unsigned short* __restrict__ W1)
{
    int rowid = (blockIdx.x << 2) + (threadIdx.x >> 6);
    int lane  = threadIdx.x & 63;
    int b     = rowid >> 9;
    const float* row = attn + (size_t)rowid * LSEQ;
    const float* hm  = hmask + (b << 9);

    float4 s0 = *(const float4*)(row + (lane << 3));
    float4 s1 = *(const float4*)(row + (lane << 3) + 4);
    float4 m0 = *(const float4*)(hm + (lane << 3));
    float4 m1 = *(const float4*)(hm + (lane << 3) + 4);

    float v[8], mk[8];
    v[0] = s0.x * m0.x; mk[0] = m0.x;
    v[1] = s0.y * m0.y; mk[1] = m0.y;
    v[2] = s0.z * m0.z; mk[2] = m0.z;
    v[3] = s0.w * m0.w; mk[3] = m0.w;
    v[4] = s1.x * m1.x; mk[4] = m1.x;
    v[5] = s1.y * m1.y; mk[5] = m1.y;
    v[6] = s1.z * m1.z; mk[6] = m1.z;
    v[7] = s1.w * m1.w; mk[7] = m1.w;

    float mx = -1e30f;
#pragma unroll
    for (int i = 0; i < 8; ++i) mx = fmaxf(mx, v[i]);
#pragma unroll
    for (int off = 32; off; off >>= 1) mx = fmaxf(mx, __shfl_xor(mx, off));

    float T = 0.f, S = 0.f;
#pragma unroll
    for (int i = 0; i < 8; ++i) {
        float e = __expf(v[i] - mx);
        S += e;
        T += mk[i] * e;
    }
#pragma unroll
    for (int off = 32; off; off >>= 1) { T += __shfl_xor(T, off); S += __shfl_xor(S, off); }

    float R = 1.f / (T + 1e-13f * S);
    if (lane == 0) { M1[rowid] = mx; R1[rowid] = R; }

    if (W1) {
        union { short8 vv; unsigned short u[8]; } wv;
#pragma unroll
        for (int i = 0; i < 8; ++i)
            wv.u[i] = f2bf(mk[i] * __expf(v[i] - mx) * R);
        *(short8*)(W1 + (size_t)rowid * LSEQ + (lane << 3)) = wv.vv;
    }
}

// ---------------------------------------------------------------------------
// K3: per (b,h) column stats over p (online masked softmax stats)
// ---------------------------------------------------------------------------
__global__ __launch_bounds__(256) void col_stats(
    const float* __restrict__ attn, const float* __restrict__ pmask,
    float* __restrict__ M2, float* __restrict__ R2)
{
    int b  = blockIdx.x >> 3;
    int h0 = (blockIdx.x & 7) << 6;
    int lane = threadIdx.x & 63;
    int wave = threadIdx.x >> 6;
    int h = h0 + lane;
    const float* Ab = attn + (size_t)b * LSEQ * LSEQ;
    const float* pm = pmask + (b << 9);

    float mx[4] = {-1e30f, -1e30f, -1e30f, -1e30f};
    float T[4]  = {0.f, 0.f, 0.f, 0.f};
    float S[4]  = {0.f, 0.f, 0.f, 0.f};

    for (int p = wave << 7; p < (wave << 7) + 128; p += 4) {
#pragma unroll
        for (int j = 0; j < 4; ++j) {
            float s = Ab[(size_t)(p + j) * LSEQ + h];
            float m = pm[p + j];
            float v = s * m;
            float nm = fmaxf(mx[j], v);
            float sc = __expf(mx[j] - nm);
            float e  = __expf(v - nm);
            T[j] = T[j] * sc + m * e;
            S[j] = S[j] * sc + e;
            mx[j] = nm;
        }
    }
    float gm = fmaxf(fmaxf(mx[0], mx[1]), fmaxf(mx[2], mx[3]));
    float gT = 0.f, gS = 0.f;
#pragma unroll
    for (int j = 0; j < 4; ++j) {
        float sc = __expf(mx[j] - gm);
        gT += T[j] * sc;
        gS += S[j] * sc;
    }

    __shared__ float sM[4][64], sT[4][64], sS[4][64];
    sM[wave][lane] = gm; sT[wave][lane] = gT; sS[wave][lane] = gS;
    __syncthreads();
    if (wave == 0) {
        float fm = sM[0][lane];
#pragma unroll
        for (int w = 1; w < 4; ++w) fm = fmaxf(fm, sM[w][lane]);
        float fT = 0.f, fS = 0.f;
#pragma unroll
        for (int w = 0; w < 4; ++w) {
            float sc = __expf(sM[w][lane] - fm);
            fT += sT[w][lane] * sc;
            fS += sS[w][lane] * sc;
        }
        M2[(b << 9) + h] = fm;
        R2[(b << 9) + h] = 1.f / (fT + 1e-13f * fS);
    }
}

// ---------------------------------------------------------------------------
// K4: W2[b][h][p] = pm[p] ? exp(attn[b][p][h]-M2[h])*R2[h] : 0  (bf16),
//     via LDS tile transpose. Tile = 64p x 128h.
// ---------------------------------------------------------------------------
__global__ __launch_bounds__(256) void w2gen(
    const float* __restrict__ attn, const float* __restrict__ pmask,
    const float* __restrict__ M2, const float* __restrict__ R2,
    unsigned short* __restrict__ W2)
{
    int blk = blockIdx.x;
    int b  = blk >> 5;
    int p0 = ((blk >> 2) & 7) << 6;
    int h0 = (blk & 3) << 7;
    const float* Ab = attn + (size_t)b * LSEQ * LSEQ;
    const float* pm = pmask + (b << 9);

    __shared__ float sM[128], sR[128];
    __shared__ unsigned short T[128 * 66];
    int t = threadIdx.x;
    if (t < 128) { sM[t] = M2[(b << 9) + h0 + t]; sR[t] = R2[(b << 9) + h0 + t]; }
    __syncthreads();

#pragma unroll
    for (int it = 0; it < 8; ++it) {
        int g  = t + (it << 8);
        int pi = g >> 5;           // 0..63
        int hc = (g & 31) << 2;    // 0..124
        float4 x = *(const float4*)(Ab + (size_t)(p0 + pi) * LSEQ + h0 + hc);
        float pv = pm[p0 + pi];
        ushort4 w;
        if (pv != 0.f) {
            w.x = f2bf(__expf(x.x - sM[hc + 0]) * sR[hc + 0]);
            w.y = f2bf(__expf(x.y - sM[hc + 1]) * sR[hc + 1]);
            w.z = f2bf(__expf(x.z - sM[hc + 2]) * sR[hc + 2]);
            w.w = f2bf(__expf(x.w - sM[hc + 3]) * sR[hc + 3]);
        } else { w.x = 0; w.y = 0; w.z = 0; w.w = 0; }
        T[(hc + 0) * 66 + pi] = w.x;
        T[(hc + 1) * 66 + pi] = w.y;
        T[(hc + 2) * 66 + pi] = w.z;
        T[(hc + 3) * 66 + pi] = w.w;
    }
    __syncthreads();

    int h  = t >> 1;
    int po = (t & 1) << 5;
    unsigned buf[16];
#pragma unroll
    for (int i = 0; i < 16; ++i)
        buf[i] = *(const unsigned*)&T[h * 66 + po + 2 * i];
    unsigned* dst = (unsigned*)(W2 + ((size_t)(b << 9) + h0 + h) * LSEQ + p0 + po);
#pragma unroll
    for (int i = 0; i < 4; ++i)
        *(uint4*)(dst + 4 * i) = *(uint4*)&buf[4 * i];
}

// ---------------------------------------------------------------------------
// K5: XT[b][d][r] = bf16(X[b][r][d])   (transpose + convert), tile 64r x 64d
// ---------------------------------------------------------------------------
__global__ __launch_bounds__(256) void transcvt(
    const float* __restrict__ X, unsigned short* __restrict__ XT)
{
    int blk = blockIdx.x;
    int b   = blk / 80;
    int rem = blk % 80;
    int r0  = (rem / 10) << 6;
    int d0  = (rem % 10) << 6;
    const float* Xb = X + (size_t)b * LSEQ * DDIM;
    unsigned short* Tb = XT + (size_t)b * DDIM * LSEQ;

    __shared__ unsigned short T[64 * 66];
    int t = threadIdx.x;
#pragma unroll
    for (int it = 0; it < 4; ++it) {
        int g  = t + (it << 8);
        int ri = g >> 4;           // 0..63
        int dc = (g & 15) << 2;    // 0..60
        if (d0 + dc < DDIM) {
            float4 x = *(const float4*)(Xb + (size_t)(r0 + ri) * DDIM + d0 + dc);
            T[(dc + 0) * 66 + ri] = f2bf(x.x);
            T[(dc + 1) * 66 + ri] = f2bf(x.y);
            T[(dc + 2) * 66 + ri] = f2bf(x.z);
            T[(dc + 3) * 66 + ri] = f2bf(x.w);
        }
    }
    __syncthreads();

    int d  = t >> 2;
    int ch = (t & 3) << 4;
    if (d0 + d < DDIM) {
        unsigned buf[8];
#pragma unroll
        for (int i = 0; i < 8; ++i)
            buf[i] = *(const unsigned*)&T[d * 66 + ch + 2 * i];
        unsigned* dst = (unsigned*)(Tb + (size_t)(d0 + d) * LSEQ + r0 + ch);
        *(uint4*)(dst)     = *(uint4*)&buf[0];
        *(uint4*)(dst + 4) = *(uint4*)&buf[4];
    }
}

// ---------------------------------------------------------------------------
// K6: out[b][m][d] = mask_m[m] * sum_k W[b][m][k] * BT[b][d][k]   (bf16 MFMA)
//     W: [B][512][512] bf16, BT: [B][600][512] bf16, out fp32 [B][512][600]
// ---------------------------------------------------------------------------
__global__ __launch_bounds__(256) void gemm_bf(
    const unsigned short* __restrict__ W, const unsigned short* __restrict__ BT,
    const float* __restrict__ mask_m, float* __restrict__ out)
{
    const int blk = blockIdx.x;
    const int b   = blk / 20;
    const int rem = blk % 20;
    const int m0  = (rem / 5) << 7;
    const int n0  = (rem % 5) << 7;
    const unsigned short* Wb = W  + (size_t)b * LSEQ * LSEQ;
    const unsigned short* Bb = BT + (size_t)b * DDIM * LSEQ;

    __shared__ unsigned short Wl[128 * LDP];
    __shared__ unsigned short Bl[128 * LDP];
    __shared__ float Mm[128];

    const int t    = threadIdx.x;
    const int lane = t & 63;
    const int wave = t >> 6;
    const int wm = (wave >> 1) << 6;
    const int wn = (wave & 1) << 6;
    const int fr = lane & 15;
    const int fq = lane >> 4;

    if (t < 128) Mm[t] = mask_m[(b << 9) + m0 + t];

    f32x4 acc[4][4];
#pragma unroll
    for (int i = 0; i < 4; ++i)
#pragma unroll
        for (int j = 0; j < 4; ++j) acc[i][j] = (f32x4){0.f, 0.f, 0.f, 0.f};

    for (int k0 = 0; k0 < LSEQ; k0 += 32) {
#pragma unroll
        for (int it = 0; it < 2; ++it) {
            int g   = t + (it << 8);
            int row = g >> 2;
            int c8  = (g & 3) << 3;
            short8 av = *(const short8*)(Wb + (size_t)(m0 + row) * LSEQ + k0 + c8);
            *(short8*)&Wl[row * LDP + c8] = av;
            int nrow = n0 + row;
            short8 bv = {0, 0, 0, 0, 0, 0, 0, 0};
            if (nrow < DDIM) bv = *(const short8*)(Bb + (size_t)nrow * LSEQ + k0 + c8);
            *(short8*)&Bl[row * LDP + c8] = bv;
        }
        __syncthreads();

        short8 af[4], bfr[4];
#pragma unroll
        for (int i = 0; i < 4; ++i) {
            af[i]  = *(const short8*)&Wl[(wm + (i << 4) + fr) * LDP + (fq << 3)];
            bfr[i] = *(const short8*)&Bl[(wn + (i << 4) + fr) * LDP + (fq << 3)];
        }
#pragma unroll
        for (int mi = 0; mi < 4; ++mi)
#pragma unroll
            for (int ni = 0; ni < 4; ++ni)
                acc[mi][ni] = mfma16(af[mi], bfr[ni], acc[mi][ni]);
        __syncthreads();
    }

#pragma unroll
    for (int mi = 0; mi < 4; ++mi)
#pragma unroll
        for (int j = 0; j < 4; ++j) {
            int row = wm + (mi << 4) + (fq << 2) + j;
            float mm = Mm[row];
#pragma unroll
            for (int ni = 0; ni < 4; ++ni) {
                int d = n0 + wn + (ni << 4) + fr;
                if (d < DDIM)
                    out[((size_t)(b << 9) + m0 + row) * DDIM + d] = mm * acc[mi][ni][j];
            }
        }
}

// ---------------------------------------------------------------------------
// Fallback (round-1) wsum — used only if ws_size is too small for fast path
// ---------------------------------------------------------------------------
template <int TRANSA>
__global__ __launch_bounds__(256) void wsum(
    const float* __restrict__ attn, const float* __restrict__ Bsrc,
    const float* __restrict__ mask_k, const float* __restrict__ mask_m,
    const float* __restrict__ Mst, const float* __restrict__ Rst,
    float* __restrict__ out)
{
    const int blk = blockIdx.x;
    const int b   = blk / 20;
    const int rem = blk % 20;
    const int m0  = (rem / 5) << 7;
    const int n0  = (rem % 5) << 7;

    const float* Ab  = attn + (size_t)b * LSEQ * LSEQ;
    const float* Bb  = Bsrc + (size_t)b * LSEQ * DDIM;
    const float* mkb = mask_k + (b << 9);

    __shared__ unsigned short Wl[128 * LDP];
    __shared__ unsigned short Bl[128 * LDP];
    __shared__ float Ml[128], Rl[128], Mm[128];

    const int t    = threadIdx.x;
    const int lane = t & 63;
    const int wave = t >> 6;
    const int wm = (wave >> 1) << 6;
    const int wn = (wave & 1) << 6;
    const int fr = lane & 15;
    const int fq = lane >> 4;

    if (t < 128) {
        Ml[t] = Mst[(b << 9) + m0 + t];
        Rl[t] = Rst[(b << 9) + m0 + t];
        Mm[t] = mask_m[(b << 9) + m0 + t];
    }
    __syncthreads();

    f32x4 acc[4][4];
#pragma unroll
    for (int i = 0; i < 4; ++i)
#pragma unroll
        for (int j = 0; j < 4; ++j) acc[i][j] = (f32x4){0.f, 0.f, 0.f, 0.f};

    for (int k0 = 0; k0 < LSEQ; k0 += 32) {
        if constexpr (TRANSA == 0) {
#pragma unroll
            for (int r = 0; r < 4; ++r) {
                int idx = t + (r << 8);
                int row = idx >> 3;
                int c4  = (idx & 7) << 2;
                float4 x  = *(const float4*)(Ab + (size_t)(m0 + row) * LSEQ + k0 + c4);
                float4 km = *(const float4*)(mkb + k0 + c4);
                float Mv = Ml[row], Rv = Rl[row];
                ushort4 w;
                w.x = (km.x != 0.f) ? f2bf(__expf(x.x - Mv) * Rv) : (unsigned short)0;
                w.y = (km.y != 0.f) ? f2bf(__expf(x.y - Mv) * Rv) : (unsigned short)0;
                w.z = (km.z != 0.f) ? f2bf(__expf(x.z - Mv) * Rv) : (unsigned short)0;
                w.w = (km.w != 0.f) ? f2bf(__expf(x.w - Mv) * Rv) : (unsigned short)0;
                *(ushort4*)&Wl[row * LDP + c4] = w;
            }
        } else {
#pragma unroll
            for (int r = 0; r < 4; ++r) {
                int mh = t & 127;
                int pq = (t >> 7) + (r << 1);
                float Mv = Ml[mh], Rv = Rl[mh];
                ushort4 w;
#pragma unroll
                for (int j = 0; j < 4; ++j) {
                    int k = k0 + (pq << 2) + j;
                    float x  = Ab[(size_t)k * LSEQ + m0 + mh];
                    float km = mkb[k];
                    ((unsigned short*)&w)[j] =
                        (km != 0.f) ? f2bf(__expf(x - Mv) * Rv) : (unsigned short)0;
                }
                *(ushort4*)&Wl[mh * LDP + (pq << 2)] = w;
            }
        }
#pragma unroll
        for (int r = 0; r < 4; ++r) {
            int d  = t & 127;
            int kq = (t >> 7) + (r << 1);
            bool valid = (n0 + d) < DDIM;
            ushort4 v;
#pragma unroll
            for (int j = 0; j < 4; ++j) {
                int k = k0 + (kq << 2) + j;
                float x = valid ? Bb[(size_t)k * DDIM + n0 + d] : 0.f;
                ((unsigned short*)&v)[j] = f2bf(x);
            }
            *(ushort4*)&Bl[d * LDP + (kq << 2)] = v;
        }
        __syncthreads();

        short8 af[4], bfr[4];
#pragma unroll
        for (int i = 0; i < 4; ++i) {
            af[i]  = *(const short8*)&Wl[(wm + (i << 4) + fr) * LDP + (fq << 3)];
            bfr[i] = *(const short8*)&Bl[(wn + (i << 4) + fr) * LDP + (fq << 3)];
        }
#pragma unroll
        for (int mi = 0; mi < 4; ++mi)
#pragma unroll
            for (int ni = 0; ni < 4; ++ni)
                acc[mi][ni] = mfma16(af[mi], bfr[ni], acc[mi][ni]);
        __syncthreads();
    }

#pragma unroll
    for (int mi = 0; mi < 4; ++mi)
#pragma unroll
        for (int j = 0; j < 4; ++j) {
            int row = wm + (mi << 4) + (fq << 2) + j;
            float mm = Mm[row];
#pragma unroll
            for (int ni = 0; ni < 4; ++ni) {
                int d = n0 + wn + (ni << 4) + fr;
                if (d < DDIM)
                    out[((size_t)(b << 9) + m0 + row) * DDIM + d] = mm * acc[mi][ni][j];
            }
        }
}

// ---------------------------------------------------------------------------
extern "C" void kernel_launch(void* const* d_in, const int* in_sizes, int n_in,
                              void* d_out, int out_size, void* d_ws, size_t ws_size,
                              hipStream_t stream)
{
    const float* P  = (const float*)d_in[0];   // encoded_premise   [64,512,600]
    const float* pm = (const float*)d_in[1];   // premise_mask      [64,512]
    const float* H  = (const float*)d_in[2];   // encoded_hypothesis[64,512,600]
    const float* hm = (const float*)d_in[3];   // hypothesis_mask   [64,512]
    float* out = (float*)d_out;
    char* ws = (char*)d_ws;

    const size_t bt_bytes   = (size_t)DEVB * DDIM * LSEQ * 2;   // 39,321,600
    const size_t w_bytes    = (size_t)DEVB * LSEQ * LSEQ * 2;   // 33,554,432
    const size_t stat_bytes = (size_t)DEVB * LSEQ * 4;          // 131,072
    const size_t fast_need  = 2 * bt_bytes + 2 * w_bytes + 4 * stat_bytes; // 146,276,352

    if (ws_size >= fast_need) {
        // fast path: attn overlays the (later-written) BT region
        float* attn = (float*)ws;
        unsigned short* hT = (unsigned short*)ws;
        unsigned short* pT = (unsigned short*)(ws + bt_bytes);
        unsigned short* W1 = (unsigned short*)(ws + 2 * bt_bytes);
        unsigned short* W2 = (unsigned short*)(ws + 2 * bt_bytes + w_bytes);
        float* M1 = (float*)(ws + 2 * bt_bytes + 2 * w_bytes);
        float* R1 = M1 + DEVB * LSEQ;
        float* M2 = R1 + DEVB * LSEQ;
        float* R2 = M2 + DEVB * LSEQ;

        attn_gemm<<<DEVB * 16, 256, 0, stream>>>(P, H, attn);
        row_stats_w1<<<DEVB * LSEQ / 4, 256, 0, stream>>>(attn, hm, M1, R1, W1);
        col_stats<<<DEVB * 8, 256, 0, stream>>>(attn, pm, M2, R2);
        w2gen<<<DEVB * 32, 256, 0, stream>>>(attn, pm, M2, R2, W2);
        // attn is dead from here on; BT overwrites its region
        transcvt<<<DEVB * 80, 256, 0, stream>>>(H, hT);
        transcvt<<<DEVB * 80, 256, 0, stream>>>(P, pT);
        gemm_bf<<<DEVB * 20, 256, 0, stream>>>(W1, hT, pm, out);
        gemm_bf<<<DEVB * 20, 256, 0, stream>>>(W2, pT, hm,
                                               out + (size_t)DEVB * LSEQ * DDIM);
    } else {
        // fallback: round-1 pipeline (needs ~64.5 MB)
        float* attn = (float*)ws;
        float* M1 = (float*)(ws + (size_t)DEVB * LSEQ * LSEQ * 4);
        float* R1 = M1 + DEVB * LSEQ;
        float* M2 = R1 + DEVB * LSEQ;
        float* R2 = M2 + DEVB * LSEQ;

        attn_gemm<<<DEVB * 16, 256, 0, stream>>>(P, H, attn);
        row_stats_w1<<<DEVB * LSEQ / 4, 256, 0, stream>>>(attn, hm, M1, R1, nullptr);
        col_stats<<<DEVB * 8, 256, 0, stream>>>(attn, pm, M2, R2);
        wsum<0><<<DEVB * 20, 256, 0, stream>>>(attn, H, hm, pm, M1, R1, out);
        wsum<1><<<DEVB * 20, 256, 0, stream>>>(attn, P, pm, hm, M2, R2,
                                               out + (size_t)DEVB * LSEQ * DDIM);
    }
}

// Round 4
// 466.951 us; speedup vs baseline: 1.5811x; 1.0343x over previous
//
#include <hip/hip_runtime.h>
#include <hip/hip_bf16.h>

#define DEVB 64
#define LSEQ 512
#define DDIM 600

typedef short short8 __attribute__((ext_vector_type(8)));
typedef float f32x4 __attribute__((ext_vector_type(4)));
typedef _Float16 f16x8 __attribute__((ext_vector_type(8)));
typedef _Float16 f16x4 __attribute__((ext_vector_type(4)));

constexpr int LDP = 40;   // padded LDS row stride (elems) for GEMM tiles

__device__ __forceinline__ unsigned short f2bf(float x) {
    union { float f; unsigned u; } v; v.f = x;
    unsigned r = v.u + 0x7fffu + ((v.u >> 16) & 1u);   // RNE
    return (unsigned short)(r >> 16);
}
__device__ __forceinline__ float bf2f(unsigned short h) {
    union { unsigned u; float f; } v; v.u = ((unsigned)h) << 16; return v.f;
}
__device__ __forceinline__ f32x4 mfma16(short8 a, short8 b, f32x4 c) {
    return __builtin_amdgcn_mfma_f32_16x16x32_bf16(a, b, c, 0, 0, 0);
}
__device__ __forceinline__ f32x4 mfma16h(f16x8 a, f16x8 b, f32x4 c) {
    return __builtin_amdgcn_mfma_f32_16x16x32_f16(a, b, c, 0, 0, 0);
}

// ---------------------------------------------------------------------------
// K1: attn[b][p][h] = sum_d P[b][p][d] * H[b][h][d]   (fp32 out)
// fp16 2-pass: A split hi/lo (exact), B hi only -> S = A*Bhi (err ~0.007)
// ---------------------------------------------------------------------------
__global__ __launch_bounds__(256) void attn_gemm(
    const float* __restrict__ P, const float* __restrict__ H,
    float* __restrict__ attn)
{
    const int blk = blockIdx.x;
    const int b  = blk >> 4;
    const int pt = ((blk >> 2) & 3) << 7;
    const int ht = (blk & 3) << 7;
    const float* Pb = P + (size_t)b * LSEQ * DDIM;
    const float* Hb = H + (size_t)b * LSEQ * DDIM;
    float* Ab = attn + (size_t)b * LSEQ * LSEQ;

    __shared__ _Float16 Ahi[128 * LDP], Alo[128 * LDP], Bhi[128 * LDP];

    const int t    = threadIdx.x;
    const int lane = t & 63;
    const int wave = t >> 6;
    const int wm = (wave >> 1) << 6;
    const int wn = (wave & 1) << 6;
    const int fr = lane & 15;
    const int fq = lane >> 4;

    f32x4 acc[4][4];
#pragma unroll
    for (int i = 0; i < 4; ++i)
#pragma unroll
        for (int j = 0; j < 4; ++j) acc[i][j] = (f32x4){0.f, 0.f, 0.f, 0.f};

    for (int k0 = 0; k0 < DDIM; k0 += 32) {
        const bool full = (k0 + 32 <= DDIM);
#pragma unroll
        for (int r = 0; r < 4; ++r) {
            int idx = t + (r << 8);
            int row = idx >> 3;
            int c4  = (idx & 7) << 2;
            // A tile (P): hi + lo fp16
            {
                const float* src = Pb + (size_t)(pt + row) * DDIM + k0 + c4;
                float x0, x1, x2, x3;
                if (full) { float4 v = *(const float4*)src; x0 = v.x; x1 = v.y; x2 = v.z; x3 = v.w; }
                else {
                    x0 = (k0 + c4 + 0 < DDIM) ? src[0] : 0.f;
                    x1 = (k0 + c4 + 1 < DDIM) ? src[1] : 0.f;
                    x2 = (k0 + c4 + 2 < DDIM) ? src[2] : 0.f;
                    x3 = (k0 + c4 + 3 < DDIM) ? src[3] : 0.f;
                }
                f16x4 hi, lo;
                hi[0] = (_Float16)x0; lo[0] = (_Float16)(x0 - (float)hi[0]);
                hi[1] = (_Float16)x1; lo[1] = (_Float16)(x1 - (float)hi[1]);
                hi[2] = (_Float16)x2; lo[2] = (_Float16)(x2 - (float)hi[2]);
                hi[3] = (_Float16)x3; lo[3] = (_Float16)(x3 - (float)hi[3]);
                *(f16x4*)&Ahi[row * LDP + c4] = hi;
                *(f16x4*)&Alo[row * LDP + c4] = lo;
            }
            // B tile (H): hi only
            {
                const float* src = Hb + (size_t)(ht + row) * DDIM + k0 + c4;
                float x0, x1, x2, x3;
                if (full) { float4 v = *(const float4*)src; x0 = v.x; x1 = v.y; x2 = v.z; x3 = v.w; }
                else {
                    x0 = (k0 + c4 + 0 < DDIM) ? src[0] : 0.f;
                    x1 = (k0 + c4 + 1 < DDIM) ? src[1] : 0.f;
                    x2 = (k0 + c4 + 2 < DDIM) ? src[2] : 0.f;
                    x3 = (k0 + c4 + 3 < DDIM) ? src[3] : 0.f;
                }
                f16x4 hi;
                hi[0] = (_Float16)x0; hi[1] = (_Float16)x1;
                hi[2] = (_Float16)x2; hi[3] = (_Float16)x3;
                *(f16x4*)&Bhi[row * LDP + c4] = hi;
            }
        }
        __syncthreads();

        f16x8 ah[4], al[4], bh[4];
#pragma unroll
        for (int i = 0; i < 4; ++i) {
            ah[i] = *(const f16x8*)&Ahi[(wm + (i << 4) + fr) * LDP + (fq << 3)];
            al[i] = *(const f16x8*)&Alo[(wm + (i << 4) + fr) * LDP + (fq << 3)];
            bh[i] = *(const f16x8*)&Bhi[(wn + (i << 4) + fr) * LDP + (fq << 3)];
        }
#pragma unroll
        for (int mi = 0; mi < 4; ++mi)
#pragma unroll
            for (int ni = 0; ni < 4; ++ni) {
                f32x4 c = acc[mi][ni];
                c = mfma16h(ah[mi], bh[ni], c);
                c = mfma16h(al[mi], bh[ni], c);
                acc[mi][ni] = c;
            }
        __syncthreads();
    }

#pragma unroll
    for (int mi = 0; mi < 4; ++mi)
#pragma unroll
        for (int ni = 0; ni < 4; ++ni)
#pragma unroll
            for (int j = 0; j < 4; ++j) {
                int p = pt + wm + (mi << 4) + (fq << 2) + j;
                int h = ht + wn + (ni << 4) + fr;
                Ab[(size_t)p * LSEQ + h] = acc[mi][ni][j];
            }
}

// ---------------------------------------------------------------------------
// K2: per (b,p) row stats over h: M=max(s*m), R=1/(T+EPS*S); optional W1 bf16
//     W1[b][p][h] = hm[h] * exp(v[h]-M) * R
// ---------------------------------------------------------------------------
__global__ __launch_bounds__(256) void row_stats_w1(
    const float* __restrict__ attn, const float* __restrict__ hmask,
    float* __restrict__ M1, float* __restrict__ R1,
    unsigned short* __restrict__ W1)
{
    int rowid = (blockIdx.x << 2) + (threadIdx.x >> 6);
    int lane  = threadIdx.x & 63;
    int b     = rowid >> 9;
    const float* row = attn + (size_t)rowid * LSEQ;
    const float* hm  = hmask + (b << 9);

    float4 s0 = *(const float4*)(row + (lane << 3));
    float4 s1 = *(const float4*)(row + (lane << 3) + 4);
    float4 m0 = *(const float4*)(hm + (lane << 3));
    float4 m1 = *(const float4*)(hm + (lane << 3) + 4);

    float v[8], mk[8];
    v[0] = s0.x * m0.x; mk[0] = m0.x;
    v[1] = s0.y * m0.y; mk[1] = m0.y;
    v[2] = s0.z * m0.z; mk[2] = m0.z;
    v[3] = s0.w * m0.w; mk[3] = m0.w;
    v[4] = s1.x * m1.x; mk[4] = m1.x;
    v[5] = s1.y * m1.y; mk[5] = m1.y;
    v[6] = s1.z * m1.z; mk[6] = m1.z;
    v[7] = s1.w * m1.w; mk[7] = m1.w;

    float mx = -1e30f;
#pragma unroll
    for (int i = 0; i < 8; ++i) mx = fmaxf(mx, v[i]);
#pragma unroll
    for (int off = 32; off; off >>= 1) mx = fmaxf(mx, __shfl_xor(mx, off));

    float T = 0.f, S = 0.f;
#pragma unroll
    for (int i = 0; i < 8; ++i) {
        float e = __expf(v[i] - mx);
        S += e;
        T += mk[i] * e;
    }
#pragma unroll
    for (int off = 32; off; off >>= 1) { T += __shfl_xor(T, off); S += __shfl_xor(S, off); }

    float R = 1.f / (T + 1e-13f * S);
    if (lane == 0) { M1[rowid] = mx; R1[rowid] = R; }

    if (W1) {
        union { short8 vv; unsigned short u[8]; } wv;
#pragma unroll
        for (int i = 0; i < 8; ++i)
            wv.u[i] = f2bf(mk[i] * __expf(v[i] - mx) * R);
        *(short8*)(W1 + (size_t)rowid * LSEQ + (lane << 3)) = wv.vv;
    }
}

// ---------------------------------------------------------------------------
// K3: per (b,h) column stats over p (online masked softmax stats)
// ---------------------------------------------------------------------------
__global__ __launch_bounds__(256) void col_stats(
    const float* __restrict__ attn, const float* __restrict__ pmask,
    float* __restrict__ M2, float* __restrict__ R2)
{
    int b  = blockIdx.x >> 3;
    int h0 = (blockIdx.x & 7) << 6;
    int lane = threadIdx.x & 63;
    int wave = threadIdx.x >> 6;
    int h = h0 + lane;
    const float* Ab = attn + (size_t)b * LSEQ * LSEQ;
    const float* pm = pmask + (b << 9);

    float mx[4] = {-1e30f, -1e30f, -1e30f, -1e30f};
    float T[4]  = {0.f, 0.f, 0.f, 0.f};
    float S[4]  = {0.f, 0.f, 0.f, 0.f};

    for (int p = wave << 7; p < (wave << 7) + 128; p += 4) {
#pragma unroll
        for (int j = 0; j < 4; ++j) {
            float s = Ab[(size_t)(p + j) * LSEQ + h];
            float m = pm[p + j];
            float v = s * m;
            float nm = fmaxf(mx[j], v);
            float sc = __expf(mx[j] - nm);
            float e  = __expf(v - nm);
            T[j] = T[j] * sc + m * e;
            S[j] = S[j] * sc + e;
            mx[j] = nm;
        }
    }
    float gm = fmaxf(fmaxf(mx[0], mx[1]), fmaxf(mx[2], mx[3]));
    float gT = 0.f, gS = 0.f;
#pragma unroll
    for (int j = 0; j < 4; ++j) {
        float sc = __expf(mx[j] - gm);
        gT += T[j] * sc;
        gS += S[j] * sc;
    }

    __shared__ float sM[4][64], sT[4][64], sS[4][64];
    sM[wave][lane] = gm; sT[wave][lane] = gT; sS[wave][lane] = gS;
    __syncthreads();
    if (wave == 0) {
        float fm = sM[0][lane];
#pragma unroll
        for (int w = 1; w < 4; ++w) fm = fmaxf(fm, sM[w][lane]);
        float fT = 0.f, fS = 0.f;
#pragma unroll
        for (int w = 0; w < 4; ++w) {
            float sc = __expf(sM[w][lane] - fm);
            fT += sT[w][lane] * sc;
            fS += sS[w][lane] * sc;
        }
        M2[(b << 9) + h] = fm;
        R2[(b << 9) + h] = 1.f / (fT + 1e-13f * fS);
    }
}

// ---------------------------------------------------------------------------
// K4: W2[b][h][p] = pm[p] ? exp(attn[b][p][h]-M2[h])*R2[h] : 0  (bf16),
//     via LDS tile transpose. Tile = 64p x 128h.
// ---------------------------------------------------------------------------
__global__ __launch_bounds__(256) void w2gen(
    const float* __restrict__ attn, const float* __restrict__ pmask,
    const float* __restrict__ M2, const float* __restrict__ R2,
    unsigned short* __restrict__ W2)
{
    int blk = blockIdx.x;
    int b  = blk >> 5;
    int p0 = ((blk >> 2) & 7) << 6;
    int h0 = (blk & 3) << 7;
    const float* Ab = attn + (size_t)b * LSEQ * LSEQ;
    const float* pm = pmask + (b << 9);

    __shared__ float sM[128], sR[128];
    __shared__ unsigned short T[128 * 66];
    int t = threadIdx.x;
    if (t < 128) { sM[t] = M2[(b << 9) + h0 + t]; sR[t] = R2[(b << 9) + h0 + t]; }
    __syncthreads();

#pragma unroll
    for (int it = 0; it < 8; ++it) {
        int g  = t + (it << 8);
        int pi = g >> 5;           // 0..63
        int hc = (g & 31) << 2;    // 0..124
        float4 x = *(const float4*)(Ab + (size_t)(p0 + pi) * LSEQ + h0 + hc);
        float pv = pm[p0 + pi];
        ushort4 w;
        if (pv != 0.f) {
            w.x = f2bf(__expf(x.x - sM[hc + 0]) * sR[hc + 0]);
            w.y = f2bf(__expf(x.y - sM[hc + 1]) * sR[hc + 1]);
            w.z = f2bf(__expf(x.z - sM[hc + 2]) * sR[hc + 2]);
            w.w = f2bf(__expf(x.w - sM[hc + 3]) * sR[hc + 3]);
        } else { w.x = 0; w.y = 0; w.z = 0; w.w = 0; }
        T[(hc + 0) * 66 + pi] = w.x;
        T[(hc + 1) * 66 + pi] = w.y;
        T[(hc + 2) * 66 + pi] = w.z;
        T[(hc + 3) * 66 + pi] = w.w;
    }
    __syncthreads();

    int h  = t >> 1;
    int po = (t & 1) << 5;
    unsigned buf[16];
#pragma unroll
    for (int i = 0; i < 16; ++i)
        buf[i] = *(const unsigned*)&T[h * 66 + po + 2 * i];
    unsigned* dst = (unsigned*)(W2 + ((size_t)(b << 9) + h0 + h) * LSEQ + p0 + po);
#pragma unroll
    for (int i = 0; i < 4; ++i)
        *(uint4*)(dst + 4 * i) = *(uint4*)&buf[4 * i];
}

// ---------------------------------------------------------------------------
// K5: XT[b][d][r] = bf16(X[b][r][d])   (transpose + convert), tile 64r x 64d
// ---------------------------------------------------------------------------
__global__ __launch_bounds__(256) void transcvt(
    const float* __restrict__ X, unsigned short* __restrict__ XT)
{
    int blk = blockIdx.x;
    int b   = blk / 80;
    int rem = blk % 80;
    int r0  = (rem / 10) << 6;
    int d0  = (rem % 10) << 6;
    const float* Xb = X + (size_t)b * LSEQ * DDIM;
    unsigned short* Tb = XT + (size_t)b * DDIM * LSEQ;

    __shared__ unsigned short T[64 * 66];
    int t = threadIdx.x;
#pragma unroll
    for (int it = 0; it < 4; ++it) {
        int g  = t + (it << 8);
        int ri = g >> 4;           // 0..63
        int dc = (g & 15) << 2;    // 0..60
        if (d0 + dc < DDIM) {
            float4 x = *(const float4*)(Xb + (size_t)(r0 + ri) * DDIM + d0 + dc);
            T[(dc + 0) * 66 + ri] = f2bf(x.x);
            T[(dc + 1) * 66 + ri] = f2bf(x.y);
            T[(dc + 2) * 66 + ri] = f2bf(x.z);
            T[(dc + 3) * 66 + ri] = f2bf(x.w);
        }
    }
    __syncthreads();

    int d  = t >> 2;
    int ch = (t & 3) << 4;
    if (d0 + d < DDIM) {
        unsigned buf[8];
#pragma unroll
        for (int i = 0; i < 8; ++i)
            buf[i] = *(const unsigned*)&T[d * 66 + ch + 2 * i];
        unsigned* dst = (unsigned*)(Tb + (size_t)(d0 + d) * LSEQ + r0 + ch);
        *(uint4*)(dst)     = *(uint4*)&buf[0];
        *(uint4*)(dst + 4) = *(uint4*)&buf[4];
    }
}

// ---------------------------------------------------------------------------
// K6: out[b][m][d] = mask_m[m] * sum_k W[b][m][k] * BT[b][d][k]   (bf16 MFMA)
//     W: [B][512][512] bf16, BT: [B][600][512] bf16, out fp32 [B][512][600]
// ---------------------------------------------------------------------------
__global__ __launch_bounds__(256) void gemm_bf(
    const unsigned short* __restrict__ W, const unsigned short* __restrict__ BT,
    const float* __restrict__ mask_m, float* __restrict__ out)
{
    const int blk = blockIdx.x;
    const int b   = blk / 20;
    const int rem = blk % 20;
    const int m0  = (rem / 5) << 7;
    const int n0  = (rem % 5) << 7;
    const unsigned short* Wb = W  + (size_t)b * LSEQ * LSEQ;
    const unsigned short* Bb = BT + (size_t)b * DDIM * LSEQ;

    __shared__ unsigned short Wl[128 * LDP];
    __shared__ unsigned short Bl[128 * LDP];
    __shared__ float Mm[128];

    const int t    = threadIdx.x;
    const int lane = t & 63;
    const int wave = t >> 6;
    const int wm = (wave >> 1) << 6;
    const int wn = (wave & 1) << 6;
    const int fr = lane & 15;
    const int fq = lane >> 4;

    if (t < 128) Mm[t] = mask_m[(b << 9) + m0 + t];

    f32x4 acc[4][4];
#pragma unroll
    for (int i = 0; i < 4; ++i)
#pragma unroll
        for (int j = 0; j < 4; ++j) acc[i][j] = (f32x4){0.f, 0.f, 0.f, 0.f};

    for (int k0 = 0; k0 < LSEQ; k0 += 32) {
#pragma unroll
        for (int it = 0; it < 2; ++it) {
            int g   = t + (it << 8);
            int row = g >> 2;
            int c8  = (g & 3) << 3;
            short8 av = *(const short8*)(Wb + (size_t)(m0 + row) * LSEQ + k0 + c8);
            *(short8*)&Wl[row * LDP + c8] = av;
            int nrow = n0 + row;
            short8 bv = {0, 0, 0, 0, 0, 0, 0, 0};
            if (nrow < DDIM) bv = *(const short8*)(Bb + (size_t)nrow * LSEQ + k0 + c8);
            *(short8*)&Bl[row * LDP + c8] = bv;
        }
        __syncthreads();

        short8 af[4], bfr[4];
#pragma unroll
        for (int i = 0; i < 4; ++i) {
            af[i]  = *(const short8*)&Wl[(wm + (i << 4) + fr) * LDP + (fq << 3)];
            bfr[i] = *(const short8*)&Bl[(wn + (i << 4) + fr) * LDP + (fq << 3)];
        }
#pragma unroll
        for (int mi = 0; mi < 4; ++mi)
#pragma unroll
            for (int ni = 0; ni < 4; ++ni)
                acc[mi][ni] = mfma16(af[mi], bfr[ni], acc[mi][ni]);
        __syncthreads();
    }

#pragma unroll
    for (int mi = 0; mi < 4; ++mi)
#pragma unroll
        for (int j = 0; j < 4; ++j) {
            int row = wm + (mi << 4) + (fq << 2) + j;
            float mm = Mm[row];
#pragma unroll
            for (int ni = 0; ni < 4; ++ni) {
                int d = n0 + wn + (ni << 4) + fr;
                if (d < DDIM)
                    out[((size_t)(b << 9) + m0 + row) * DDIM + d] = mm * acc[mi][ni][j];
            }
        }
}

// ---------------------------------------------------------------------------
// Fallback (round-1) wsum — used only if ws_size is too small for fast path
// ---------------------------------------------------------------------------
template <int TRANSA>
__global__ __launch_bounds__(256) void wsum(
    const float* __restrict__ attn, const float* __restrict__ Bsrc,
    const float* __restrict__ mask_k, const float* __restrict__ mask_m,
    const float* __restrict__ Mst, const float* __restrict__ Rst,
    float* __restrict__ out)
{
    const int blk = blockIdx.x;
    const int b   = blk / 20;
    const int rem = blk % 20;
    const int m0  = (rem / 5) << 7;
    const int n0  = (rem % 5) << 7;

    const float* Ab  = attn + (size_t)b * LSEQ * LSEQ;
    const float* Bb  = Bsrc + (size_t)b * LSEQ * DDIM;
    const float* mkb = mask_k + (b << 9);

    __shared__ unsigned short Wl[128 * LDP];
    __shared__ unsigned short Bl[128 * LDP];
    __shared__ float Ml[128], Rl[128], Mm[128];

    const int t    = threadIdx.x;
    const int lane = t & 63;
    const int wave = t >> 6;
    const int wm = (wave >> 1) << 6;
    const int wn = (wave & 1) << 6;
    const int fr = lane & 15;
    const int fq = lane >> 4;

    if (t < 128) {
        Ml[t] = Mst[(b << 9) + m0 + t];
        Rl[t] = Rst[(b << 9) + m0 + t];
        Mm[t] = mask_m[(b << 9) + m0 + t];
    }
    __syncthreads();

    f32x4 acc[4][4];
#pragma unroll
    for (int i = 0; i < 4; ++i)
#pragma unroll
        for (int j = 0; j < 4; ++j) acc[i][j] = (f32x4){0.f, 0.f, 0.f, 0.f};

    for (int k0 = 0; k0 < LSEQ; k0 += 32) {
        if constexpr (TRANSA == 0) {
#pragma unroll
            for (int r = 0; r < 4; ++r) {
                int idx = t + (r << 8);
                int row = idx >> 3;
                int c4  = (idx & 7) << 2;
                float4 x  = *(const float4*)(Ab + (size_t)(m0 + row) * LSEQ + k0 + c4);
                float4 km = *(const float4*)(mkb + k0 + c4);
                float Mv = Ml[row], Rv = Rl[row];
                ushort4 w;
                w.x = (km.x != 0.f) ? f2bf(__expf(x.x - Mv) * Rv) : (unsigned short)0;
                w.y = (km.y != 0.f) ? f2bf(__expf(x.y - Mv) * Rv) : (unsigned short)0;
                w.z = (km.z != 0.f) ? f2bf(__expf(x.z - Mv) * Rv) : (unsigned short)0;
                w.w = (km.w != 0.f) ? f2bf(__expf(x.w - Mv) * Rv) : (unsigned short)0;
                *(ushort4*)&Wl[row * LDP + c4] = w;
            }
        } else {
#pragma unroll
            for (int r = 0; r < 4; ++r) {
                int mh = t & 127;
                int pq = (t >> 7) + (r << 1);
                float Mv = Ml[mh], Rv = Rl[mh];
                ushort4 w;
#pragma unroll
                for (int j = 0; j < 4; ++j) {
                    int k = k0 + (pq << 2) + j;
                    float x  = Ab[(size_t)k * LSEQ + m0 + mh];
                    float km = mkb[k];
                    ((unsigned short*)&w)[j] =
                        (km != 0.f) ? f2bf(__expf(x - Mv) * Rv) : (unsigned short)0;
                }
                *(ushort4*)&Wl[mh * LDP + (pq << 2)] = w;
            }
        }
#pragma unroll
        for (int r = 0; r < 4; ++r) {
            int d  = t & 127;
            int kq = (t >> 7) + (r << 1);
            bool valid = (n0 + d) < DDIM;
            ushort4 v;
#pragma unroll
            for (int j = 0; j < 4; ++j) {
                int k = k0 + (kq << 2) + j;
                float x = valid ? Bb[(size_t)k * DDIM + n0 + d] : 0.f;
                ((unsigned short*)&v)[j] = f2bf(x);
            }
            *(ushort4*)&Bl[d * LDP + (kq << 2)] = v;
        }
        __syncthreads();

        short8 af[4], bfr[4];
#pragma unroll
        for (int i = 0; i < 4; ++i) {
            af[i]  = *(const short8*)&Wl[(wm + (i << 4) + fr) * LDP + (fq << 3)];
            bfr[i] = *(const short8*)&Bl[(wn + (i << 4) + fr) * LDP + (fq << 3)];
        }
#pragma unroll
        for (int mi = 0; mi < 4; ++mi)
#pragma unroll
            for (int ni = 0; ni < 4; ++ni)
                acc[mi][ni] = mfma16(af[mi], bfr[ni], acc[mi][ni]);
        __syncthreads();
    }

#pragma unroll
    for (int mi = 0; mi < 4; ++mi)
#pragma unroll
        for (int j = 0; j < 4; ++j) {
            int row = wm + (mi << 4) + (fq << 2) + j;
            float mm = Mm[row];
#pragma unroll
            for (int ni = 0; ni < 4; ++ni) {
                int d = n0 + wn + (ni << 4) + fr;
                if (d < DDIM)
                    out[((size_t)(b << 9) + m0 + row) * DDIM + d] = mm * acc[mi][ni][j];
            }
        }
}

// ---------------------------------------------------------------------------
extern "C" void kernel_launch(void* const* d_in, const int* in_sizes, int n_in,
                              void* d_out, int out_size, void* d_ws, size_t ws_size,
                              hipStream_t stream)
{
    const float* P  = (const float*)d_in[0];   // encoded_premise   [64,512,600]
    const float* pm = (const float*)d_in[1];   // premise_mask      [64,512]
    const float* H  = (const float*)d_in[2];   // encoded_hypothesis[64,512,600]
    const float* hm = (const float*)d_in[3];   // hypothesis_mask   [64,512]
    float* out = (float*)d_out;
    char* ws = (char*)d_ws;

    const size_t bt_bytes   = (size_t)DEVB * DDIM * LSEQ * 2;   // 39,321,600
    const size_t w_bytes    = (size_t)DEVB * LSEQ * LSEQ * 2;   // 33,554,432
    const size_t stat_bytes = (size_t)DEVB * LSEQ * 4;          // 131,072
    const size_t fast_need  = 2 * bt_bytes + 2 * w_bytes + 4 * stat_bytes; // 146,276,352

    if (ws_size >= fast_need) {
        // fast path: attn overlays the (later-written) BT region
        float* attn = (float*)ws;
        unsigned short* hT = (unsigned short*)ws;
        unsigned short* pT = (unsigned short*)(ws + bt_bytes);
        unsigned short* W1 = (unsigned short*)(ws + 2 * bt_bytes);
        unsigned short* W2 = (unsigned short*)(ws + 2 * bt_bytes + w_bytes);
        float* M1 = (float*)(ws + 2 * bt_bytes + 2 * w_bytes);
        float* R1 = M1 + DEVB * LSEQ;
        float* M2 = R1 + DEVB * LSEQ;
        float* R2 = M2 + DEVB * LSEQ;

        attn_gemm<<<DEVB * 16, 256, 0, stream>>>(P, H, attn);
        row_stats_w1<<<DEVB * LSEQ / 4, 256, 0, stream>>>(attn, hm, M1, R1, W1);
        col_stats<<<DEVB * 8, 256, 0, stream>>>(attn, pm, M2, R2);
        w2gen<<<DEVB * 32, 256, 0, stream>>>(attn, pm, M2, R2, W2);
        // attn is dead from here on; BT overwrites its region
        transcvt<<<DEVB * 80, 256, 0, stream>>>(H, hT);
        transcvt<<<DEVB * 80, 256, 0, stream>>>(P, pT);
        gemm_bf<<<DEVB * 20, 256, 0, stream>>>(W1, hT, pm, out);
        gemm_bf<<<DEVB * 20, 256, 0, stream>>>(W2, pT, hm,
                                               out + (size_t)DEVB * LSEQ * DDIM);
    } else {
        // fallback: round-1 pipeline (needs ~64.5 MB)
        float* attn = (float*)ws;
        float* M1 = (float*)(ws + (size_t)DEVB * LSEQ * LSEQ * 4);
        float* R1 = M1 + DEVB * LSEQ;
        float* M2 = R1 + DEVB * LSEQ;
        float* R2 = M2 + DEVB * LSEQ;

        attn_gemm<<<DEVB * 16, 256, 0, stream>>>(P, H, attn);
        row_stats_w1<<<DEVB * LSEQ / 4, 256, 0, stream>>>(attn, hm, M1, R1, nullptr);
        col_stats<<<DEVB * 8, 256, 0, stream>>>(attn, pm, M2, R2);
        wsum<0><<<DEVB * 20, 256, 0, stream>>>(attn, H, hm, pm, M1, R1, out);
        wsum<1><<<DEVB * 20, 256, 0, stream>>>(attn, P, pm, hm, M2, R2,
                                               out + (size_t)DEVB * LSEQ * DDIM);
    }
}

// Round 5
// 335.230 us; speedup vs baseline: 2.2023x; 1.3929x over previous
//
#include <hip/hip_runtime.h>
#include <hip/hip_bf16.h>

#define DEVB 64
#define LSEQ 512
#define DDIM 600
#define KPAD 608   // 600 rounded up to 32; zero-padded tail -> uniform K loop

typedef short short8 __attribute__((ext_vector_type(8)));
typedef float f32x4 __attribute__((ext_vector_type(4)));
typedef _Float16 f16x8 __attribute__((ext_vector_type(8)));
typedef _Float16 f16x4 __attribute__((ext_vector_type(4)));

constexpr int LDP = 40;   // padded LDS row stride (elems): 80 B rows -> ~2-way conflicts max

__device__ __forceinline__ unsigned short f2bf(float x) {
    union { float f; unsigned u; } v; v.f = x;
    unsigned r = v.u + 0x7fffu + ((v.u >> 16) & 1u);   // RNE
    return (unsigned short)(r >> 16);
}
__device__ __forceinline__ f32x4 mfma16(short8 a, short8 b, f32x4 c) {
    return __builtin_amdgcn_mfma_f32_16x16x32_bf16(a, b, c, 0, 0, 0);
}
__device__ __forceinline__ f32x4 mfma16h(f16x8 a, f16x8 b, f32x4 c) {
    return __builtin_amdgcn_mfma_f32_16x16x32_f16(a, b, c, 0, 0, 0);
}

// ---------------------------------------------------------------------------
// K0: prep — X[rows][600] fp32 -> Xhi (and optionally Xlo) [rows][608] fp16,
//     zero-padded tail. Pure memory-bound. rows = DEVB*LSEQ.
// ---------------------------------------------------------------------------
__global__ __launch_bounds__(256) void prep(
    const float* __restrict__ X, _Float16* __restrict__ Xhi,
    _Float16* __restrict__ Xlo)
{
    int g = blockIdx.x * 256 + threadIdx.x;       // row*152 + slot
    int row  = g / 152;
    int slot = g - row * 152;
    int d = slot << 2;
    f16x4 hi = {0, 0, 0, 0}, lo = {0, 0, 0, 0};
    if (d < DDIM) {
        float4 x = *(const float4*)(X + (size_t)row * DDIM + d);
        hi[0] = (_Float16)x.x; lo[0] = (_Float16)(x.x - (float)hi[0]);
        hi[1] = (_Float16)x.y; lo[1] = (_Float16)(x.y - (float)hi[1]);
        hi[2] = (_Float16)x.z; lo[2] = (_Float16)(x.z - (float)hi[2]);
        hi[3] = (_Float16)x.w; lo[3] = (_Float16)(x.w - (float)hi[3]);
    }
    *(f16x4*)(Xhi + (size_t)row * KPAD + d) = hi;
    if (Xlo) *(f16x4*)(Xlo + (size_t)row * KPAD + d) = lo;
}

// ---------------------------------------------------------------------------
// K1: attn[b][p][h] = sum_d P[b][p][d] * H[b][h][d]   (fp32 out)
// Pure fp16 GEMM from prepacked Phi/Plo/Hhi; S = (Phi+Plo)*Hhi.
// Issue-early register prefetch; XCD-swizzled blocks.
// ---------------------------------------------------------------------------
__global__ __launch_bounds__(256) void attn_gemm(
    const _Float16* __restrict__ Phi, const _Float16* __restrict__ Plo,
    const _Float16* __restrict__ Hhi, float* __restrict__ attn)
{
    const int bid = blockIdx.x;
    const int swz = (bid & 7) * 128 + (bid >> 3);   // 1024 blocks, 8 XCDs
    const int b  = swz >> 4;
    const int pt = ((swz >> 2) & 3) << 7;
    const int ht = (swz & 3) << 7;
    const _Float16* Pbh = Phi + (size_t)b * LSEQ * KPAD;
    const _Float16* Pbl = Plo + (size_t)b * LSEQ * KPAD;
    const _Float16* Hb  = Hhi + (size_t)b * LSEQ * KPAD;
    float* Ab = attn + (size_t)b * LSEQ * LSEQ;

    __shared__ _Float16 Ah[128 * LDP], Al[128 * LDP], Bh[128 * LDP];

    const int t    = threadIdx.x;
    const int lane = t & 63;
    const int wave = t >> 6;
    const int wm = (wave >> 1) << 6;
    const int wn = (wave & 1) << 6;
    const int fr = lane & 15;
    const int fq = lane >> 4;

    // staging address components (idx = t + r*256 covers 128 rows x 4 col-chunks)
    const int srow = t >> 2;            // row for r=0 (r=1 adds 64)
    const int sc8  = (t & 3) << 3;      // col chunk (8 fp16)

    f16x8 pf[6];
    auto issue = [&](int k0) {
#pragma unroll
        for (int r = 0; r < 2; ++r) {
            int row = srow + (r << 6);
            const size_t off = (size_t)row * KPAD + k0 + sc8;
            pf[r * 3 + 0] = *(const f16x8*)(Pbh + (size_t)(pt)*KPAD + off);
            pf[r * 3 + 1] = *(const f16x8*)(Pbl + (size_t)(pt)*KPAD + off);
            pf[r * 3 + 2] = *(const f16x8*)(Hb  + (size_t)(ht)*KPAD + off);
        }
    };
    issue(0);

    f32x4 acc[4][4];
#pragma unroll
    for (int i = 0; i < 4; ++i)
#pragma unroll
        for (int j = 0; j < 4; ++j) acc[i][j] = (f32x4){0.f, 0.f, 0.f, 0.f};

    constexpr int NK = KPAD / 32;   // 19
    for (int it = 0; it < NK; ++it) {
        // write phase (prev-iteration readers finished at loop-end barrier)
#pragma unroll
        for (int r = 0; r < 2; ++r) {
            int row = srow + (r << 6);
            *(f16x8*)&Ah[row * LDP + sc8] = pf[r * 3 + 0];
            *(f16x8*)&Al[row * LDP + sc8] = pf[r * 3 + 1];
            *(f16x8*)&Bh[row * LDP + sc8] = pf[r * 3 + 2];
        }
        __syncthreads();
        if (it + 1 < NK) issue((it + 1) << 5);   // overlap with ds_read + MFMA

        f16x8 ah[4], al[4], bh[4];
#pragma unroll
        for (int i = 0; i < 4; ++i) {
            ah[i] = *(const f16x8*)&Ah[(wm + (i << 4) + fr) * LDP + (fq << 3)];
            al[i] = *(const f16x8*)&Al[(wm + (i << 4) + fr) * LDP + (fq << 3)];
            bh[i] = *(const f16x8*)&Bh[(wn + (i << 4) + fr) * LDP + (fq << 3)];
        }
#pragma unroll
        for (int mi = 0; mi < 4; ++mi)
#pragma unroll
            for (int ni = 0; ni < 4; ++ni) {
                f32x4 c = acc[mi][ni];
                c = mfma16h(ah[mi], bh[ni], c);
                c = mfma16h(al[mi], bh[ni], c);
                acc[mi][ni] = c;
            }
        __syncthreads();
    }

#pragma unroll
    for (int mi = 0; mi < 4; ++mi)
#pragma unroll
        for (int ni = 0; ni < 4; ++ni)
#pragma unroll
            for (int j = 0; j < 4; ++j) {
                int p = pt + wm + (mi << 4) + (fq << 2) + j;
                int h = ht + wn + (ni << 4) + fr;
                Ab[(size_t)p * LSEQ + h] = acc[mi][ni][j];
            }
}

// ---------------------------------------------------------------------------
// K2: per (b,p) row stats over h: M=max(s*m), R=1/(T+EPS*S); optional W1 bf16
// ---------------------------------------------------------------------------
__global__ __launch_bounds__(256) void row_stats_w1(
    const float* __restrict__ attn, const float* __restrict__ hmask,
    float* __restrict__ M1, float* __restrict__ R1,
    unsigned short* __restrict__ W1)
{
    int rowid = (blockIdx.x << 2) + (threadIdx.x >> 6);
    int lane  = threadIdx.x & 63;
    int b     = rowid >> 9;
    const float* row = attn + (size_t)rowid * LSEQ;
    const float* hm  = hmask + (b << 9);

    float4 s0 = *(const float4*)(row + (lane << 3));
    float4 s1 = *(const float4*)(row + (lane << 3) + 4);
    float4 m0 = *(const float4*)(hm + (lane << 3));
    float4 m1 = *(const float4*)(hm + (lane << 3) + 4);

    float v[8], mk[8];
    v[0] = s0.x * m0.x; mk[0] = m0.x;
    v[1] = s0.y * m0.y; mk[1] = m0.y;
    v[2] = s0.z * m0.z; mk[2] = m0.z;
    v[3] = s0.w * m0.w; mk[3] = m0.w;
    v[4] = s1.x * m1.x; mk[4] = m1.x;
    v[5] = s1.y * m1.y; mk[5] = m1.y;
    v[6] = s1.z * m1.z; mk[6] = m1.z;
    v[7] = s1.w * m1.w; mk[7] = m1.w;

    float mx = -1e30f;
#pragma unroll
    for (int i = 0; i < 8; ++i) mx = fmaxf(mx, v[i]);
#pragma unroll
    for (int off = 32; off; off >>= 1) mx = fmaxf(mx, __shfl_xor(mx, off));

    float T = 0.f, S = 0.f;
#pragma unroll
    for (int i = 0; i < 8; ++i) {
        float e = __expf(v[i] - mx);
        S += e;
        T += mk[i] * e;
    }
#pragma unroll
    for (int off = 32; off; off >>= 1) { T += __shfl_xor(T, off); S += __shfl_xor(S, off); }

    float R = 1.f / (T + 1e-13f * S);
    if (lane == 0) { M1[rowid] = mx; R1[rowid] = R; }

    if (W1) {
        union { short8 vv; unsigned short u[8]; } wv;
#pragma unroll
        for (int i = 0; i < 8; ++i)
            wv.u[i] = f2bf(mk[i] * __expf(v[i] - mx) * R);
        *(short8*)(W1 + (size_t)rowid * LSEQ + (lane << 3)) = wv.vv;
    }
}

// ---------------------------------------------------------------------------
// K3: per (b,h) column stats over p (online masked softmax stats)
// ---------------------------------------------------------------------------
__global__ __launch_bounds__(256) void col_stats(
    const float* __restrict__ attn, const float* __restrict__ pmask,
    float* __restrict__ M2, float* __restrict__ R2)
{
    int b  = blockIdx.x >> 3;
    int h0 = (blockIdx.x & 7) << 6;
    int lane = threadIdx.x & 63;
    int wave = threadIdx.x >> 6;
    int h = h0 + lane;
    const float* Ab = attn + (size_t)b * LSEQ * LSEQ;
    const float* pm = pmask + (b << 9);

    float mx[4] = {-1e30f, -1e30f, -1e30f, -1e30f};
    float T[4]  = {0.f, 0.f, 0.f, 0.f};
    float S[4]  = {0.f, 0.f, 0.f, 0.f};

    for (int p = wave << 7; p < (wave << 7) + 128; p += 4) {
#pragma unroll
        for (int j = 0; j < 4; ++j) {
            float s = Ab[(size_t)(p + j) * LSEQ + h];
            float m = pm[p + j];
            float v = s * m;
            float nm = fmaxf(mx[j], v);
            float sc = __expf(mx[j] - nm);
            float e  = __expf(v - nm);
            T[j] = T[j] * sc + m * e;
            S[j] = S[j] * sc + e;
            mx[j] = nm;
        }
    }
    float gm = fmaxf(fmaxf(mx[0], mx[1]), fmaxf(mx[2], mx[3]));
    float gT = 0.f, gS = 0.f;
#pragma unroll
    for (int j = 0; j < 4; ++j) {
        float sc = __expf(mx[j] - gm);
        gT += T[j] * sc;
        gS += S[j] * sc;
    }

    __shared__ float sM[4][64], sT[4][64], sS[4][64];
    sM[wave][lane] = gm; sT[wave][lane] = gT; sS[wave][lane] = gS;
    __syncthreads();
    if (wave == 0) {
        float fm = sM[0][lane];
#pragma unroll
        for (int w = 1; w < 4; ++w) fm = fmaxf(fm, sM[w][lane]);
        float fT = 0.f, fS = 0.f;
#pragma unroll
        for (int w = 0; w < 4; ++w) {
            float sc = __expf(sM[w][lane] - fm);
            fT += sT[w][lane] * sc;
            fS += sS[w][lane] * sc;
        }
        M2[(b << 9) + h] = fm;
        R2[(b << 9) + h] = 1.f / (fT + 1e-13f * fS);
    }
}

// ---------------------------------------------------------------------------
// K4: W2[b][h][p] = pm[p] ? exp(attn[b][p][h]-M2[h])*R2[h] : 0  (bf16),
//     via LDS tile transpose. Tile = 64p x 128h.
// ---------------------------------------------------------------------------
__global__ __launch_bounds__(256) void w2gen(
    const float* __restrict__ attn, const float* __restrict__ pmask,
    const float* __restrict__ M2, const float* __restrict__ R2,
    unsigned short* __restrict__ W2)
{
    int blk = blockIdx.x;
    int b  = blk >> 5;
    int p0 = ((blk >> 2) & 7) << 6;
    int h0 = (blk & 3) << 7;
    const float* Ab = attn + (size_t)b * LSEQ * LSEQ;
    const float* pm = pmask + (b << 9);

    __shared__ float sM[128], sR[128];
    __shared__ unsigned short T[128 * 66];
    int t = threadIdx.x;
    if (t < 128) { sM[t] = M2[(b << 9) + h0 + t]; sR[t] = R2[(b << 9) + h0 + t]; }
    __syncthreads();

#pragma unroll
    for (int it = 0; it < 8; ++it) {
        int g  = t + (it << 8);
        int pi = g >> 5;           // 0..63
        int hc = (g & 31) << 2;    // 0..124
        float4 x = *(const float4*)(Ab + (size_t)(p0 + pi) * LSEQ + h0 + hc);
        float pv = pm[p0 + pi];
        ushort4 w;
        if (pv != 0.f) {
            w.x = f2bf(__expf(x.x - sM[hc + 0]) * sR[hc + 0]);
            w.y = f2bf(__expf(x.y - sM[hc + 1]) * sR[hc + 1]);
            w.z = f2bf(__expf(x.z - sM[hc + 2]) * sR[hc + 2]);
            w.w = f2bf(__expf(x.w - sM[hc + 3]) * sR[hc + 3]);
        } else { w.x = 0; w.y = 0; w.z = 0; w.w = 0; }
        T[(hc + 0) * 66 + pi] = w.x;
        T[(hc + 1) * 66 + pi] = w.y;
        T[(hc + 2) * 66 + pi] = w.z;
        T[(hc + 3) * 66 + pi] = w.w;
    }
    __syncthreads();

    int h  = t >> 1;
    int po = (t & 1) << 5;
    unsigned buf[16];
#pragma unroll
    for (int i = 0; i < 16; ++i)
        buf[i] = *(const unsigned*)&T[h * 66 + po + 2 * i];
    unsigned* dst = (unsigned*)(W2 + ((size_t)(b << 9) + h0 + h) * LSEQ + p0 + po);
#pragma unroll
    for (int i = 0; i < 4; ++i)
        *(uint4*)(dst + 4 * i) = *(uint4*)&buf[4 * i];
}

// ---------------------------------------------------------------------------
// K5: XT[b][d][r] = bf16(X[b][r][d])   (transpose + convert), tile 64r x 64d
// ---------------------------------------------------------------------------
__global__ __launch_bounds__(256) void transcvt(
    const float* __restrict__ X, unsigned short* __restrict__ XT)
{
    int blk = blockIdx.x;
    int b   = blk / 80;
    int rem = blk % 80;
    int r0  = (rem / 10) << 6;
    int d0  = (rem % 10) << 6;
    const float* Xb = X + (size_t)b * LSEQ * DDIM;
    unsigned short* Tb = XT + (size_t)b * DDIM * LSEQ;

    __shared__ unsigned short T[64 * 66];
    int t = threadIdx.x;
#pragma unroll
    for (int it = 0; it < 4; ++it) {
        int g  = t + (it << 8);
        int ri = g >> 4;           // 0..63
        int dc = (g & 15) << 2;    // 0..60
        if (d0 + dc < DDIM) {
            float4 x = *(const float4*)(Xb + (size_t)(r0 + ri) * DDIM + d0 + dc);
            T[(dc + 0) * 66 + ri] = f2bf(x.x);
            T[(dc + 1) * 66 + ri] = f2bf(x.y);
            T[(dc + 2) * 66 + ri] = f2bf(x.z);
            T[(dc + 3) * 66 + ri] = f2bf(x.w);
        }
    }
    __syncthreads();

    int d  = t >> 2;
    int ch = (t & 3) << 4;
    if (d0 + d < DDIM) {
        unsigned buf[8];
#pragma unroll
        for (int i = 0; i < 8; ++i)
            buf[i] = *(const unsigned*)&T[d * 66 + ch + 2 * i];
        unsigned* dst = (unsigned*)(Tb + (size_t)(d0 + d) * LSEQ + r0 + ch);
        *(uint4*)(dst)     = *(uint4*)&buf[0];
        *(uint4*)(dst + 4) = *(uint4*)&buf[4];
    }
}

// ---------------------------------------------------------------------------
// K6: out[b][m][d] = mask_m[m] * sum_k W[b][m][k] * BT[b][d][k]   (bf16 MFMA)
//     Issue-early prefetch + XCD swizzle.
// ---------------------------------------------------------------------------
__global__ __launch_bounds__(256) void gemm_bf(
    const unsigned short* __restrict__ W, const unsigned short* __restrict__ BT,
    const float* __restrict__ mask_m, float* __restrict__ out)
{
    const int bid = blockIdx.x;
    const int swz = (bid & 7) * 160 + (bid >> 3);   // 1280 blocks, 8 XCDs
    const int b   = swz / 20;
    const int rem = swz % 20;
    const int m0  = (rem / 5) << 7;
    const int n0  = (rem % 5) << 7;
    const unsigned short* Wb = W  + (size_t)b * LSEQ * LSEQ;
    const unsigned short* Bb = BT + (size_t)b * DDIM * LSEQ;

    __shared__ unsigned short Wl[128 * LDP];
    __shared__ unsigned short Bl[128 * LDP];
    __shared__ float Mm[128];

    const int t    = threadIdx.x;
    const int lane = t & 63;
    const int wave = t >> 6;
    const int wm = (wave >> 1) << 6;
    const int wn = (wave & 1) << 6;
    const int fr = lane & 15;
    const int fq = lane >> 4;

    if (t < 128) Mm[t] = mask_m[(b << 9) + m0 + t];

    const int srow = t >> 2;
    const int sc8  = (t & 3) << 3;

    short8 pw[2], pb[2];
    auto issue = [&](int k0) {
#pragma unroll
        for (int r = 0; r < 2; ++r) {
            int row = srow + (r << 6);
            pw[r] = *(const short8*)(Wb + (size_t)(m0 + row) * LSEQ + k0 + sc8);
            int nrow = n0 + row;
            short8 bv = {0, 0, 0, 0, 0, 0, 0, 0};
            if (nrow < DDIM) bv = *(const short8*)(Bb + (size_t)nrow * LSEQ + k0 + sc8);
            pb[r] = bv;
        }
    };
    issue(0);

    f32x4 acc[4][4];
#pragma unroll
    for (int i = 0; i < 4; ++i)
#pragma unroll
        for (int j = 0; j < 4; ++j) acc[i][j] = (f32x4){0.f, 0.f, 0.f, 0.f};

    for (int k0 = 0; k0 < LSEQ; k0 += 32) {
#pragma unroll
        for (int r = 0; r < 2; ++r) {
            int row = srow + (r << 6);
            *(short8*)&Wl[row * LDP + sc8] = pw[r];
            *(short8*)&Bl[row * LDP + sc8] = pb[r];
        }
        __syncthreads();
        if (k0 + 32 < LSEQ) issue(k0 + 32);

        short8 af[4], bfr[4];
#pragma unroll
        for (int i = 0; i < 4; ++i) {
            af[i]  = *(const short8*)&Wl[(wm + (i << 4) + fr) * LDP + (fq << 3)];
            bfr[i] = *(const short8*)&Bl[(wn + (i << 4) + fr) * LDP + (fq << 3)];
        }
#pragma unroll
        for (int mi = 0; mi < 4; ++mi)
#pragma unroll
            for (int ni = 0; ni < 4; ++ni)
                acc[mi][ni] = mfma16(af[mi], bfr[ni], acc[mi][ni]);
        __syncthreads();
    }

#pragma unroll
    for (int mi = 0; mi < 4; ++mi)
#pragma unroll
        for (int j = 0; j < 4; ++j) {
            int row = wm + (mi << 4) + (fq << 2) + j;
            float mm = Mm[row];
#pragma unroll
            for (int ni = 0; ni < 4; ++ni) {
                int d = n0 + wn + (ni << 4) + fr;
                if (d < DDIM)
                    out[((size_t)(b << 9) + m0 + row) * DDIM + d] = mm * acc[mi][ni][j];
            }
        }
}

// ---------------------------------------------------------------------------
// Fallback wsum — used only if ws_size is too small for fast path
// ---------------------------------------------------------------------------
template <int TRANSA>
__global__ __launch_bounds__(256) void wsum(
    const float* __restrict__ attn, const float* __restrict__ Bsrc,
    const float* __restrict__ mask_k, const float* __restrict__ mask_m,
    const float* __restrict__ Mst, const float* __restrict__ Rst,
    float* __restrict__ out)
{
    const int blk = blockIdx.x;
    const int b   = blk / 20;
    const int rem = blk % 20;
    const int m0  = (rem / 5) << 7;
    const int n0  = (rem % 5) << 7;

    const float* Ab  = attn + (size_t)b * LSEQ * LSEQ;
    const float* Bb  = Bsrc + (size_t)b * LSEQ * DDIM;
    const float* mkb = mask_k + (b << 9);

    __shared__ unsigned short Wl[128 * LDP];
    __shared__ unsigned short Bl[128 * LDP];
    __shared__ float Ml[128], Rl[128], Mm[128];

    const int t    = threadIdx.x;
    const int lane = t & 63;
    const int wave = t >> 6;
    const int wm = (wave >> 1) << 6;
    const int wn = (wave & 1) << 6;
    const int fr = lane & 15;
    const int fq = lane >> 4;

    if (t < 128) {
        Ml[t] = Mst[(b << 9) + m0 + t];
        Rl[t] = Rst[(b << 9) + m0 + t];
        Mm[t] = mask_m[(b << 9) + m0 + t];
    }
    __syncthreads();

    f32x4 acc[4][4];
#pragma unroll
    for (int i = 0; i < 4; ++i)
#pragma unroll
        for (int j = 0; j < 4; ++j) acc[i][j] = (f32x4){0.f, 0.f, 0.f, 0.f};

    for (int k0 = 0; k0 < LSEQ; k0 += 32) {
        if constexpr (TRANSA == 0) {
#pragma unroll
            for (int r = 0; r < 4; ++r) {
                int idx = t + (r << 8);
                int row = idx >> 3;
                int c4  = (idx & 7) << 2;
                float4 x  = *(const float4*)(Ab + (size_t)(m0 + row) * LSEQ + k0 + c4);
                float4 km = *(const float4*)(mkb + k0 + c4);
                float Mv = Ml[row], Rv = Rl[row];
                ushort4 w;
                w.x = (km.x != 0.f) ? f2bf(__expf(x.x - Mv) * Rv) : (unsigned short)0;
                w.y = (km.y != 0.f) ? f2bf(__expf(x.y - Mv) * Rv) : (unsigned short)0;
                w.z = (km.z != 0.f) ? f2bf(__expf(x.z - Mv) * Rv) : (unsigned short)0;
                w.w = (km.w != 0.f) ? f2bf(__expf(x.w - Mv) * Rv) : (unsigned short)0;
                *(ushort4*)&Wl[row * LDP + c4] = w;
            }
        } else {
#pragma unroll
            for (int r = 0; r < 4; ++r) {
                int mh = t & 127;
                int pq = (t >> 7) + (r << 1);
                float Mv = Ml[mh], Rv = Rl[mh];
                ushort4 w;
#pragma unroll
                for (int j = 0; j < 4; ++j) {
                    int k = k0 + (pq << 2) + j;
                    float x  = Ab[(size_t)k * LSEQ + m0 + mh];
                    float km = mkb[k];
                    ((unsigned short*)&w)[j] =
                        (km != 0.f) ? f2bf(__expf(x - Mv) * Rv) : (unsigned short)0;
                }
                *(ushort4*)&Wl[mh * LDP + (pq << 2)] = w;
            }
        }
#pragma unroll
        for (int r = 0; r < 4; ++r) {
            int d  = t & 127;
            int kq = (t >> 7) + (r << 1);
            bool valid = (n0 + d) < DDIM;
            ushort4 v;
#pragma unroll
            for (int j = 0; j < 4; ++j) {
                int k = k0 + (kq << 2) + j;
                float x = valid ? Bb[(size_t)k * DDIM + n0 + d] : 0.f;
                ((unsigned short*)&v)[j] = f2bf(x);
            }
            *(ushort4*)&Bl[d * LDP + (kq << 2)] = v;
        }
        __syncthreads();

        short8 af[4], bfr[4];
#pragma unroll
        for (int i = 0; i < 4; ++i) {
            af[i]  = *(const short8*)&Wl[(wm + (i << 4) + fr) * LDP + (fq << 3)];
            bfr[i] = *(const short8*)&Bl[(wn + (i << 4) + fr) * LDP + (fq << 3)];
        }
#pragma unroll
        for (int mi = 0; mi < 4; ++mi)
#pragma unroll
            for (int ni = 0; ni < 4; ++ni)
                acc[mi][ni] = mfma16(af[mi], bfr[ni], acc[mi][ni]);
        __syncthreads();
    }

#pragma unroll
    for (int mi = 0; mi < 4; ++mi)
#pragma unroll
        for (int j = 0; j < 4; ++j) {
            int row = wm + (mi << 4) + (fq << 2) + j;
            float mm = Mm[row];
#pragma unroll
            for (int ni = 0; ni < 4; ++ni) {
                int d = n0 + wn + (ni << 4) + fr;
                if (d < DDIM)
                    out[((size_t)(b << 9) + m0 + row) * DDIM + d] = mm * acc[mi][ni][j];
            }
        }
}

// ---------------------------------------------------------------------------
extern "C" void kernel_launch(void* const* d_in, const int* in_sizes, int n_in,
                              void* d_out, int out_size, void* d_ws, size_t ws_size,
                              hipStream_t stream)
{
    const float* P  = (const float*)d_in[0];   // encoded_premise   [64,512,600]
    const float* pm = (const float*)d_in[1];   // premise_mask      [64,512]
    const float* H  = (const float*)d_in[2];   // encoded_hypothesis[64,512,600]
    const float* hm = (const float*)d_in[3];   // hypothesis_mask   [64,512]
    float* out = (float*)d_out;
    char* ws = (char*)d_ws;

    // fp16 prepacked operands live in d_out (dead until final gemm_bf writes):
    // Phi, Plo, Hhi each DEVB*LSEQ*KPAD fp16 = 39.85 MB; total 119.5 MB < 157.3 MB
    const size_t pk_elems = (size_t)DEVB * LSEQ * KPAD;
    _Float16* Phi = (_Float16*)d_out;
    _Float16* Plo = Phi + pk_elems;
    _Float16* Hhi = Plo + pk_elems;

    const size_t bt_bytes   = (size_t)DEVB * DDIM * LSEQ * 2;   // 39,321,600
    const size_t w_bytes    = (size_t)DEVB * LSEQ * LSEQ * 2;   // 33,554,432
    const size_t stat_bytes = (size_t)DEVB * LSEQ * 4;          // 131,072
    const size_t fast_need  = 2 * bt_bytes + 2 * w_bytes + 4 * stat_bytes; // 146,276,352

    const int prep_grid = DEVB * LSEQ * 152 / 256;   // 19456

    if (ws_size >= fast_need) {
        float* attn = (float*)ws;
        unsigned short* hT = (unsigned short*)ws;                 // overlays attn later
        unsigned short* pT = (unsigned short*)(ws + bt_bytes);
        unsigned short* W1 = (unsigned short*)(ws + 2 * bt_bytes);
        unsigned short* W2 = (unsigned short*)(ws + 2 * bt_bytes + w_bytes);
        float* M1 = (float*)(ws + 2 * bt_bytes + 2 * w_bytes);
        float* R1 = M1 + DEVB * LSEQ;
        float* M2 = R1 + DEVB * LSEQ;
        float* R2 = M2 + DEVB * LSEQ;

        prep<<<prep_grid, 256, 0, stream>>>(P, Phi, Plo);
        prep<<<prep_grid, 256, 0, stream>>>(H, Hhi, nullptr);
        attn_gemm<<<DEVB * 16, 256, 0, stream>>>(Phi, Plo, Hhi, attn);
        row_stats_w1<<<DEVB * LSEQ / 4, 256, 0, stream>>>(attn, hm, M1, R1, W1);
        col_stats<<<DEVB * 8, 256, 0, stream>>>(attn, pm, M2, R2);
        w2gen<<<DEVB * 32, 256, 0, stream>>>(attn, pm, M2, R2, W2);
        // attn dead; BT overwrites its region
        transcvt<<<DEVB * 80, 256, 0, stream>>>(H, hT);
        transcvt<<<DEVB * 80, 256, 0, stream>>>(P, pT);
        // Phi/Plo/Hhi dead; gemm_bf overwrites d_out with the real outputs
        gemm_bf<<<DEVB * 20, 256, 0, stream>>>(W1, hT, pm, out);
        gemm_bf<<<DEVB * 20, 256, 0, stream>>>(W2, pT, hm,
                                               out + (size_t)DEVB * LSEQ * DDIM);
    } else {
        float* attn = (float*)ws;
        float* M1 = (float*)(ws + (size_t)DEVB * LSEQ * LSEQ * 4);
        float* R1 = M1 + DEVB * LSEQ;
        float* M2 = R1 + DEVB * LSEQ;
        float* R2 = M2 + DEVB * LSEQ;

        prep<<<prep_grid, 256, 0, stream>>>(P, Phi, Plo);
        prep<<<prep_grid, 256, 0, stream>>>(H, Hhi, nullptr);
        attn_gemm<<<DEVB * 16, 256, 0, stream>>>(Phi, Plo, Hhi, attn);
        row_stats_w1<<<DEVB * LSEQ / 4, 256, 0, stream>>>(attn, hm, M1, R1, nullptr);
        col_stats<<<DEVB * 8, 256, 0, stream>>>(attn, pm, M2, R2);
        wsum<0><<<DEVB * 20, 256, 0, stream>>>(attn, H, hm, pm, M1, R1, out);
        wsum<1><<<DEVB * 20, 256, 0, stream>>>(attn, P, pm, hm, M2, R2,
                                               out + (size_t)DEVB * LSEQ * DDIM);
    }
}

// Round 6
// 327.052 us; speedup vs baseline: 2.2574x; 1.0250x over previous
//
#include <hip/hip_runtime.h>
#include <hip/hip_bf16.h>

#define DEVB 64
#define LSEQ 512
#define DDIM 600

typedef short short8 __attribute__((ext_vector_type(8)));
typedef float f32x4 __attribute__((ext_vector_type(4)));
typedef _Float16 f16x8 __attribute__((ext_vector_type(8)));
typedef _Float16 f16x4 __attribute__((ext_vector_type(4)));

constexpr int LDP = 40;   // padded LDS row stride (elems): 80B rows -> ~2-way conflicts max

__device__ __forceinline__ unsigned short f2bf(float x) {
    union { float f; unsigned u; } v; v.f = x;
    unsigned r = v.u + 0x7fffu + ((v.u >> 16) & 1u);   // RNE
    return (unsigned short)(r >> 16);
}
__device__ __forceinline__ f32x4 mfma16(short8 a, short8 b, f32x4 c) {
    return __builtin_amdgcn_mfma_f32_16x16x32_bf16(a, b, c, 0, 0, 0);
}
__device__ __forceinline__ f32x4 mfma16h(f16x8 a, f16x8 b, f32x4 c) {
    return __builtin_amdgcn_mfma_f32_16x16x32_f16(a, b, c, 0, 0, 0);
}

// ---------------------------------------------------------------------------
// K0: prep_t — one read of X[b][512][600] fp32 produces:
//   Xhi (fp16 hi, row-major [seq][600]), optional Xlo (fp16 residual),
//   optional XT (fp16 transpose [600][512]) via LDS tile transpose.
// Tile 64 rows x 64 cols.
// ---------------------------------------------------------------------------
__global__ __launch_bounds__(256) void prep_t(
    const float* __restrict__ X, _Float16* __restrict__ Xhi,
    _Float16* __restrict__ Xlo, _Float16* __restrict__ XT)
{
    int blk = blockIdx.x;
    int b   = blk / 80;
    int rem = blk % 80;
    int r0  = (rem / 10) << 6;
    int d0  = (rem % 10) << 6;
    const float* Xb = X + (size_t)b * LSEQ * DDIM;
    _Float16* Hib = Xhi + (size_t)b * LSEQ * DDIM;
    _Float16* Lob = Xlo ? (Xlo + (size_t)b * LSEQ * DDIM) : nullptr;

    __shared__ _Float16 T[64 * 66];
    int t = threadIdx.x;
#pragma unroll
    for (int it = 0; it < 4; ++it) {
        int g  = t + (it << 8);
        int ri = g >> 4;           // 0..63
        int dc = (g & 15) << 2;    // 0..60
        if (d0 + dc < DDIM) {
            float4 x = *(const float4*)(Xb + (size_t)(r0 + ri) * DDIM + d0 + dc);
            f16x4 hi, lo;
            hi[0] = (_Float16)x.x; lo[0] = (_Float16)(x.x - (float)hi[0]);
            hi[1] = (_Float16)x.y; lo[1] = (_Float16)(x.y - (float)hi[1]);
            hi[2] = (_Float16)x.z; lo[2] = (_Float16)(x.z - (float)hi[2]);
            hi[3] = (_Float16)x.w; lo[3] = (_Float16)(x.w - (float)hi[3]);
            *(f16x4*)(Hib + (size_t)(r0 + ri) * DDIM + d0 + dc) = hi;
            if (Lob) *(f16x4*)(Lob + (size_t)(r0 + ri) * DDIM + d0 + dc) = lo;
            T[(dc + 0) * 66 + ri] = hi[0];
            T[(dc + 1) * 66 + ri] = hi[1];
            T[(dc + 2) * 66 + ri] = hi[2];
            T[(dc + 3) * 66 + ri] = hi[3];
        }
    }
    if (XT) {
        __syncthreads();
        int d  = t >> 2;
        int ch = (t & 3) << 4;
        if (d0 + d < DDIM) {
            unsigned buf[8];
#pragma unroll
            for (int i = 0; i < 8; ++i)
                buf[i] = *(const unsigned*)&T[d * 66 + ch + 2 * i];
            unsigned* dst = (unsigned*)(XT + ((size_t)b * DDIM + d0 + d) * LSEQ + r0 + ch);
            *(uint4*)(dst)     = *(uint4*)&buf[0];
            *(uint4*)(dst + 4) = *(uint4*)&buf[4];
        }
    }
}

// ---------------------------------------------------------------------------
// K1: attn[b][p][h] = sum_d P[b][p][d] * H[b][h][d]   (fp32 out)
// fp16 2-pass from prepacked Phi/Plo/Hhi (stride 600, tail chunk zeroed).
// Single-barrier LDS double-buffer + issue-early prefetch + XCD swizzle.
// ---------------------------------------------------------------------------
__global__ __launch_bounds__(256) void attn_gemm(
    const _Float16* __restrict__ Phi, const _Float16* __restrict__ Plo,
    const _Float16* __restrict__ Hhi, float* __restrict__ attn)
{
    const int bid = blockIdx.x;
    const int swz = (bid & 7) * 128 + (bid >> 3);   // 1024 blocks, 8 XCDs
    const int b  = swz >> 4;
    const int pt = ((swz >> 2) & 3) << 7;
    const int ht = (swz & 3) << 7;
    const _Float16* Pbh = Phi + ((size_t)b * LSEQ + pt) * DDIM;
    const _Float16* Pbl = Plo + ((size_t)b * LSEQ + pt) * DDIM;
    const _Float16* Hb  = Hhi + ((size_t)b * LSEQ + ht) * DDIM;
    float* Ab = attn + (size_t)b * LSEQ * LSEQ;

    __shared__ _Float16 Ah[2][128 * LDP], Al[2][128 * LDP], Bh[2][128 * LDP];

    const int t    = threadIdx.x;
    const int lane = t & 63;
    const int wave = t >> 6;
    const int wm = (wave >> 1) << 6;
    const int wn = (wave & 1) << 6;
    const int fr = lane & 15;
    const int fq = lane >> 4;
    const int srow = t >> 2;          // 0..63 (r=1 adds 64)
    const int sc8  = (t & 3) << 3;    // col chunk (8 fp16)

    f16x8 pf[6];
    const f16x8 zz = {0, 0, 0, 0, 0, 0, 0, 0};
    auto issue = [&](int k0) {
        bool ok = (k0 + sc8) < DDIM;   // zero the 600..607 tail chunk
#pragma unroll
        for (int r = 0; r < 2; ++r) {
            size_t off = (size_t)(srow + (r << 6)) * DDIM + k0 + sc8;
            pf[r * 3 + 0] = ok ? *(const f16x8*)(Pbh + off) : zz;
            pf[r * 3 + 1] = ok ? *(const f16x8*)(Pbl + off) : zz;
            pf[r * 3 + 2] = ok ? *(const f16x8*)(Hb  + off) : zz;
        }
    };
    auto wr = [&](int buf) {
#pragma unroll
        for (int r = 0; r < 2; ++r) {
            int row = srow + (r << 6);
            *(f16x8*)&Ah[buf][row * LDP + sc8] = pf[r * 3 + 0];
            *(f16x8*)&Al[buf][row * LDP + sc8] = pf[r * 3 + 1];
            *(f16x8*)&Bh[buf][row * LDP + sc8] = pf[r * 3 + 2];
        }
    };

    issue(0);
    wr(0);
    issue(32);
    __syncthreads();

    f32x4 acc[4][4];
#pragma unroll
    for (int i = 0; i < 4; ++i)
#pragma unroll
        for (int j = 0; j < 4; ++j) acc[i][j] = (f32x4){0.f, 0.f, 0.f, 0.f};

    constexpr int NK = 19;   // ceil(600/32)
    int cur = 0;
    for (int it = 0; it < NK; ++it) {
        f16x8 ah[4], al[4], bh[4];
#pragma unroll
        for (int i = 0; i < 4; ++i) {
            ah[i] = *(const f16x8*)&Ah[cur][(wm + (i << 4) + fr) * LDP + (fq << 3)];
            al[i] = *(const f16x8*)&Al[cur][(wm + (i << 4) + fr) * LDP + (fq << 3)];
            bh[i] = *(const f16x8*)&Bh[cur][(wn + (i << 4) + fr) * LDP + (fq << 3)];
        }
        if (it + 1 < NK) {
            wr(cur ^ 1);                       // stage tile it+1 into other buffer
            if (it + 2 < NK) issue((it + 2) << 5);
        }
#pragma unroll
        for (int mi = 0; mi < 4; ++mi)
#pragma unroll
            for (int ni = 0; ni < 4; ++ni) {
                f32x4 c = acc[mi][ni];
                c = mfma16h(ah[mi], bh[ni], c);
                c = mfma16h(al[mi], bh[ni], c);
                acc[mi][ni] = c;
            }
        __syncthreads();
        cur ^= 1;
    }

#pragma unroll
    for (int mi = 0; mi < 4; ++mi)
#pragma unroll
        for (int ni = 0; ni < 4; ++ni)
#pragma unroll
            for (int j = 0; j < 4; ++j) {
                int p = pt + wm + (mi << 4) + (fq << 2) + j;
                int h = ht + wn + (ni << 4) + fr;
                Ab[(size_t)p * LSEQ + h] = acc[mi][ni][j];
            }
}

// ---------------------------------------------------------------------------
// K2: stats_w1 — ONE pass over attn per 64-row stripe:
//   per-row (over h): M1, R1, W1 fp16 (hm-masked softmax)
//   per-col partials (over p, pm-masked online): Mp/Tp/Sp [b][8][512]
// grid = DEVB*8, block 256 (4 waves x 16 rows each)
// ---------------------------------------------------------------------------
__global__ __launch_bounds__(256) void stats_w1(
    const float* __restrict__ attn, const float* __restrict__ hmask,
    const float* __restrict__ pmask,
    float* __restrict__ M1, float* __restrict__ R1,
    _Float16* __restrict__ W1,
    float* __restrict__ Mp, float* __restrict__ Tp, float* __restrict__ Sp)
{
    int b      = blockIdx.x >> 3;
    int stripe = blockIdx.x & 7;
    int lane   = threadIdx.x & 63;
    int wave   = threadIdx.x >> 6;
    const float* hm = hmask + (b << 9);
    const float* pm = pmask + (b << 9);

    float4 m0 = *(const float4*)(hm + (lane << 3));
    float4 m1 = *(const float4*)(hm + (lane << 3) + 4);
    float mk[8] = {m0.x, m0.y, m0.z, m0.w, m1.x, m1.y, m1.z, m1.w};

    float cM[8], cT[8], cS[8];
#pragma unroll
    for (int j = 0; j < 8; ++j) { cM[j] = -1e30f; cT[j] = 0.f; cS[j] = 0.f; }

    for (int i = 0; i < 16; ++i) {
        int row   = (stripe << 6) + (wave << 4) + i;
        int rowid = (b << 9) + row;
        const float* rp = attn + (size_t)rowid * LSEQ + (lane << 3);
        float4 s0 = *(const float4*)rp;
        float4 s1 = *(const float4*)(rp + 4);
        float s[8] = {s0.x, s0.y, s0.z, s0.w, s1.x, s1.y, s1.z, s1.w};

        float v[8];
#pragma unroll
        for (int j = 0; j < 8; ++j) v[j] = s[j] * mk[j];
        float mx = -1e30f;
#pragma unroll
        for (int j = 0; j < 8; ++j) mx = fmaxf(mx, v[j]);
#pragma unroll
        for (int off = 32; off; off >>= 1) mx = fmaxf(mx, __shfl_xor(mx, off));

        float e[8], T = 0.f, S = 0.f;
#pragma unroll
        for (int j = 0; j < 8; ++j) { e[j] = __expf(v[j] - mx); T += mk[j] * e[j]; S += e[j]; }
#pragma unroll
        for (int off = 32; off; off >>= 1) { T += __shfl_xor(T, off); S += __shfl_xor(S, off); }
        float R = 1.f / (T + 1e-13f * S);

        if (W1) {
            union { f16x8 v8; _Float16 h[8]; } wv;
#pragma unroll
            for (int j = 0; j < 8; ++j) wv.h[j] = (_Float16)(mk[j] * e[j] * R);
            *(f16x8*)(W1 + (size_t)rowid * LSEQ + (lane << 3)) = wv.v8;
        }
        if (lane == 0) { M1[rowid] = mx; R1[rowid] = R; }

        float pmv = pm[row];
#pragma unroll
        for (int j = 0; j < 8; ++j) {
            float v2 = s[j] * pmv;
            float nm = fmaxf(cM[j], v2);
            float sc = __expf(cM[j] - nm);
            float e2 = __expf(v2 - nm);
            cT[j] = cT[j] * sc + pmv * e2;
            cS[j] = cS[j] * sc + e2;
            cM[j] = nm;
        }
    }

    __shared__ float LM[4][512], LT[4][512], LS[4][512];
#pragma unroll
    for (int j = 0; j < 8; ++j) {
        int c = (lane << 3) + j;
        LM[wave][c] = cM[j]; LT[wave][c] = cT[j]; LS[wave][c] = cS[j];
    }
    __syncthreads();

    size_t base = (size_t)((b << 3) + stripe) * 512;
    for (int cc = threadIdx.x; cc < 512; cc += 256) {
        float gm = fmaxf(fmaxf(LM[0][cc], LM[1][cc]), fmaxf(LM[2][cc], LM[3][cc]));
        float gT = 0.f, gS = 0.f;
#pragma unroll
        for (int w = 0; w < 4; ++w) {
            float sc = __expf(LM[w][cc] - gm);
            gT += LT[w][cc] * sc;
            gS += LS[w][cc] * sc;
        }
        Mp[base + cc] = gm; Tp[base + cc] = gT; Sp[base + cc] = gS;
    }
}

// ---------------------------------------------------------------------------
// K3: col_merge — merge 8 stripe partials -> M2, R2. grid = DEVB*2, block 256
// ---------------------------------------------------------------------------
__global__ __launch_bounds__(256) void col_merge(
    const float* __restrict__ Mp, const float* __restrict__ Tp,
    const float* __restrict__ Sp, float* __restrict__ M2, float* __restrict__ R2)
{
    int b = blockIdx.x >> 1;
    int c = ((blockIdx.x & 1) << 8) + threadIdx.x;
    float gm = -1e30f, gT = 0.f, gS = 0.f;
#pragma unroll
    for (int st = 0; st < 8; ++st) {
        size_t idx = (size_t)((b << 3) + st) * 512 + c;
        float m = Mp[idx], tt = Tp[idx], ss = Sp[idx];
        float nm  = fmaxf(gm, m);
        float sc1 = __expf(gm - nm), sc2 = __expf(m - nm);
        gT = gT * sc1 + tt * sc2;
        gS = gS * sc1 + ss * sc2;
        gm = nm;
    }
    M2[(b << 9) + c] = gm;
    R2[(b << 9) + c] = 1.f / (gT + 1e-13f * gS);
}

// ---------------------------------------------------------------------------
// K4: w2gen — W2[b][h][p] = pm[p] ? exp(attn[b][p][h]-M2[h])*R2[h] : 0 (fp16)
//     via LDS tile transpose. Tile = 64p x 128h.
// ---------------------------------------------------------------------------
__global__ __launch_bounds__(256) void w2gen(
    const float* __restrict__ attn, const float* __restrict__ pmask,
    const float* __restrict__ M2, const float* __restrict__ R2,
    _Float16* __restrict__ W2)
{
    int blk = blockIdx.x;
    int b  = blk >> 5;
    int p0 = ((blk >> 2) & 7) << 6;
    int h0 = (blk & 3) << 7;
    const float* Ab = attn + (size_t)b * LSEQ * LSEQ;
    const float* pm = pmask + (b << 9);

    __shared__ float sM[128], sR[128];
    __shared__ _Float16 T[128 * 66];
    int t = threadIdx.x;
    if (t < 128) { sM[t] = M2[(b << 9) + h0 + t]; sR[t] = R2[(b << 9) + h0 + t]; }
    __syncthreads();

#pragma unroll
    for (int it = 0; it < 8; ++it) {
        int g  = t + (it << 8);
        int pi = g >> 5;           // 0..63
        int hc = (g & 31) << 2;    // 0..124
        float4 x = *(const float4*)(Ab + (size_t)(p0 + pi) * LSEQ + h0 + hc);
        float pv = pm[p0 + pi];
        _Float16 w0 = 0, w1 = 0, w2 = 0, w3 = 0;
        if (pv != 0.f) {
            w0 = (_Float16)(__expf(x.x - sM[hc + 0]) * sR[hc + 0]);
            w1 = (_Float16)(__expf(x.y - sM[hc + 1]) * sR[hc + 1]);
            w2 = (_Float16)(__expf(x.z - sM[hc + 2]) * sR[hc + 2]);
            w3 = (_Float16)(__expf(x.w - sM[hc + 3]) * sR[hc + 3]);
        }
        T[(hc + 0) * 66 + pi] = w0;
        T[(hc + 1) * 66 + pi] = w1;
        T[(hc + 2) * 66 + pi] = w2;
        T[(hc + 3) * 66 + pi] = w3;
    }
    __syncthreads();

    int h  = t >> 1;
    int po = (t & 1) << 5;
    unsigned buf[16];
#pragma unroll
    for (int i = 0; i < 16; ++i)
        buf[i] = *(const unsigned*)&T[h * 66 + po + 2 * i];
    unsigned* dst = (unsigned*)(W2 + ((size_t)(b << 9) + h0 + h) * LSEQ + p0 + po);
#pragma unroll
    for (int i = 0; i < 4; ++i)
        *(uint4*)(dst + 4 * i) = *(uint4*)&buf[4 * i];
}

// ---------------------------------------------------------------------------
// K5: out[b][m][d] = mask_m[m] * sum_k W[b][m][k] * BT[b][d][k]   (fp16 MFMA)
//     W: [B][512][512] f16, BT: [B][600][512] f16, out fp32 [B][512][600]
//     Single-barrier double-buffer + issue-early prefetch + XCD swizzle.
// ---------------------------------------------------------------------------
__global__ __launch_bounds__(256) void gemm_fp16(
    const _Float16* __restrict__ W, const _Float16* __restrict__ BT,
    const float* __restrict__ mask_m, float* __restrict__ out)
{
    const int bid = blockIdx.x;
    const int swz = (bid & 7) * 160 + (bid >> 3);   // 1280 blocks, 8 XCDs
    const int b   = swz / 20;
    const int rem = swz % 20;
    const int m0  = (rem / 5) << 7;
    const int n0  = (rem % 5) << 7;
    const _Float16* Wb = W  + (size_t)b * LSEQ * LSEQ;
    const _Float16* Bb = BT + (size_t)b * DDIM * LSEQ;

    __shared__ _Float16 Wl[2][128 * LDP];
    __shared__ _Float16 Bl[2][128 * LDP];
    __shared__ float Mm[128];

    const int t    = threadIdx.x;
    const int lane = t & 63;
    const int wave = t >> 6;
    const int wm = (wave >> 1) << 6;
    const int wn = (wave & 1) << 6;
    const int fr = lane & 15;
    const int fq = lane >> 4;
    const int srow = t >> 2;
    const int sc8  = (t & 3) << 3;

    if (t < 128) Mm[t] = mask_m[(b << 9) + m0 + t];

    f16x8 pw[2], pb[2];
    const f16x8 zz = {0, 0, 0, 0, 0, 0, 0, 0};
    auto issue = [&](int k0) {
#pragma unroll
        for (int r = 0; r < 2; ++r) {
            int row = srow + (r << 6);
            pw[r] = *(const f16x8*)(Wb + (size_t)(m0 + row) * LSEQ + k0 + sc8);
            int nrow = n0 + row;
            pb[r] = (nrow < DDIM) ? *(const f16x8*)(Bb + (size_t)nrow * LSEQ + k0 + sc8) : zz;
        }
    };
    auto wr = [&](int buf) {
#pragma unroll
        for (int r = 0; r < 2; ++r) {
            int row = srow + (r << 6);
            *(f16x8*)&Wl[buf][row * LDP + sc8] = pw[r];
            *(f16x8*)&Bl[buf][row * LDP + sc8] = pb[r];
        }
    };

    issue(0);
    wr(0);
    issue(32);
    __syncthreads();

    f32x4 acc[4][4];
#pragma unroll
    for (int i = 0; i < 4; ++i)
#pragma unroll
        for (int j = 0; j < 4; ++j) acc[i][j] = (f32x4){0.f, 0.f, 0.f, 0.f};

    constexpr int NK = 16;   // 512/32
    int cur = 0;
    for (int it = 0; it < NK; ++it) {
        f16x8 af[4], bfr[4];
#pragma unroll
        for (int i = 0; i < 4; ++i) {
            af[i]  = *(const f16x8*)&Wl[cur][(wm + (i << 4) + fr) * LDP + (fq << 3)];
            bfr[i] = *(const f16x8*)&Bl[cur][(wn + (i << 4) + fr) * LDP + (fq << 3)];
        }
        if (it + 1 < NK) {
            wr(cur ^ 1);
            if (it + 2 < NK) issue((it + 2) << 5);
        }
#pragma unroll
        for (int mi = 0; mi < 4; ++mi)
#pragma unroll
            for (int ni = 0; ni < 4; ++ni)
                acc[mi][ni] = mfma16h(af[mi], bfr[ni], acc[mi][ni]);
        __syncthreads();
        cur ^= 1;
    }

#pragma unroll
    for (int mi = 0; mi < 4; ++mi)
#pragma unroll
        for (int j = 0; j < 4; ++j) {
            int row = wm + (mi << 4) + (fq << 2) + j;
            float mm = Mm[row];
#pragma unroll
            for (int ni = 0; ni < 4; ++ni) {
                int d = n0 + wn + (ni << 4) + fr;
                if (d < DDIM)
                    out[((size_t)(b << 9) + m0 + row) * DDIM + d] = mm * acc[mi][ni][j];
            }
        }
}

// ---------------------------------------------------------------------------
// Fallback wsum (round-1 style) — only if ws_size too small for fast path
// ---------------------------------------------------------------------------
template <int TRANSA>
__global__ __launch_bounds__(256) void wsum(
    const float* __restrict__ attn, const float* __restrict__ Bsrc,
    const float* __restrict__ mask_k, const float* __restrict__ mask_m,
    const float* __restrict__ Mst, const float* __restrict__ Rst,
    float* __restrict__ out)
{
    const int blk = blockIdx.x;
    const int b   = blk / 20;
    const int rem = blk % 20;
    const int m0  = (rem / 5) << 7;
    const int n0  = (rem % 5) << 7;

    const float* Ab  = attn + (size_t)b * LSEQ * LSEQ;
    const float* Bb  = Bsrc + (size_t)b * LSEQ * DDIM;
    const float* mkb = mask_k + (b << 9);

    __shared__ unsigned short Wl[128 * LDP];
    __shared__ unsigned short Bl[128 * LDP];
    __shared__ float Ml[128], Rl[128], Mm[128];

    const int t    = threadIdx.x;
    const int lane = t & 63;
    const int wave = t >> 6;
    const int wm = (wave >> 1) << 6;
    const int wn = (wave & 1) << 6;
    const int fr = lane & 15;
    const int fq = lane >> 4;

    if (t < 128) {
        Ml[t] = Mst[(b << 9) + m0 + t];
        Rl[t] = Rst[(b << 9) + m0 + t];
        Mm[t] = mask_m[(b << 9) + m0 + t];
    }
    __syncthreads();

    f32x4 acc[4][4];
#pragma unroll
    for (int i = 0; i < 4; ++i)
#pragma unroll
        for (int j = 0; j < 4; ++j) acc[i][j] = (f32x4){0.f, 0.f, 0.f, 0.f};

    for (int k0 = 0; k0 < LSEQ; k0 += 32) {
        if constexpr (TRANSA == 0) {
#pragma unroll
            for (int r = 0; r < 4; ++r) {
                int idx = t + (r << 8);
                int row = idx >> 3;
                int c4  = (idx & 7) << 2;
                float4 x  = *(const float4*)(Ab + (size_t)(m0 + row) * LSEQ + k0 + c4);
                float4 km = *(const float4*)(mkb + k0 + c4);
                float Mv = Ml[row], Rv = Rl[row];
                ushort4 w;
                w.x = (km.x != 0.f) ? f2bf(__expf(x.x - Mv) * Rv) : (unsigned short)0;
                w.y = (km.y != 0.f) ? f2bf(__expf(x.y - Mv) * Rv) : (unsigned short)0;
                w.z = (km.z != 0.f) ? f2bf(__expf(x.z - Mv) * Rv) : (unsigned short)0;
                w.w = (km.w != 0.f) ? f2bf(__expf(x.w - Mv) * Rv) : (unsigned short)0;
                *(ushort4*)&Wl[row * LDP + c4] = w;
            }
        } else {
#pragma unroll
            for (int r = 0; r < 4; ++r) {
                int mh = t & 127;
                int pq = (t >> 7) + (r << 1);
                float Mv = Ml[mh], Rv = Rl[mh];
                ushort4 w;
#pragma unroll
                for (int j = 0; j < 4; ++j) {
                    int k = k0 + (pq << 2) + j;
                    float x  = Ab[(size_t)k * LSEQ + m0 + mh];
                    float km = mkb[k];
                    ((unsigned short*)&w)[j] =
                        (km != 0.f) ? f2bf(__expf(x - Mv) * Rv) : (unsigned short)0;
                }
                *(ushort4*)&Wl[mh * LDP + (pq << 2)] = w;
            }
        }
#pragma unroll
        for (int r = 0; r < 4; ++r) {
            int d  = t & 127;
            int kq = (t >> 7) + (r << 1);
            bool valid = (n0 + d) < DDIM;
            ushort4 v;
#pragma unroll
            for (int j = 0; j < 4; ++j) {
                int k = k0 + (kq << 2) + j;
                float x = valid ? Bb[(size_t)k * DDIM + n0 + d] : 0.f;
                ((unsigned short*)&v)[j] = f2bf(x);
            }
            *(ushort4*)&Bl[d * LDP + (kq << 2)] = v;
        }
        __syncthreads();

        short8 af[4], bfr[4];
#pragma unroll
        for (int i = 0; i < 4; ++i) {
            af[i]  = *(const short8*)&Wl[(wm + (i << 4) + fr) * LDP + (fq << 3)];
            bfr[i] = *(const short8*)&Bl[(wn + (i << 4) + fr) * LDP + (fq << 3)];
        }
#pragma unroll
        for (int mi = 0; mi < 4; ++mi)
#pragma unroll
            for (int ni = 0; ni < 4; ++ni)
                acc[mi][ni] = mfma16(af[mi], bfr[ni], acc[mi][ni]);
        __syncthreads();
    }

#pragma unroll
    for (int mi = 0; mi < 4; ++mi)
#pragma unroll
        for (int j = 0; j < 4; ++j) {
            int row = wm + (mi << 4) + (fq << 2) + j;
            float mm = Mm[row];
#pragma unroll
            for (int ni = 0; ni < 4; ++ni) {
                int d = n0 + wn + (ni << 4) + fr;
                if (d < DDIM)
                    out[((size_t)(b << 9) + m0 + row) * DDIM + d] = mm * acc[mi][ni][j];
            }
        }
}

// ---------------------------------------------------------------------------
extern "C" void kernel_launch(void* const* d_in, const int* in_sizes, int n_in,
                              void* d_out, int out_size, void* d_ws, size_t ws_size,
                              hipStream_t stream)
{
    const float* P  = (const float*)d_in[0];   // encoded_premise   [64,512,600]
    const float* pm = (const float*)d_in[1];   // premise_mask      [64,512]
    const float* H  = (const float*)d_in[2];   // encoded_hypothesis[64,512,600]
    const float* hm = (const float*)d_in[3];   // hypothesis_mask   [64,512]
    float* out = (float*)d_out;
    char* o  = (char*)d_out;
    char* ws = (char*)d_ws;

    const size_t E = (size_t)DEVB * LSEQ * DDIM;   // 19,660,800 elems (39,321,600 B f16)

    // d_out scratch layout (all dead before the gemms write their regions):
    //   Phi [0 : 39.32M) | Plo [39.32 : 78.64M) | Hhi [78.64 : 117.96M) | hT [117.96 : 157.29M)
    //   W1 overlays dead Hhi after attn_gemm.
    _Float16* Phi = (_Float16*)o;
    _Float16* Plo = Phi + E;
    _Float16* Hhi = Plo + E;
    _Float16* hT  = Hhi + E;                        // exactly fills d_out
    _Float16* W1  = Hhi;                            // 33.55 MB <= 39.32 MB slot

    // ws layout (fast path, 143,654,912 B needed):
    //   attn fp32 [0 : 67.11M) | pT [67.11 : 106.43M) | W2 [106.43 : 139.98M)
    //   Mp/Tp/Sp [139.98 : 143.13M) | M1/R1/M2/R2 [143.13 : 143.65M)
    const size_t fast_need = 143654912;

    if (ws_size >= fast_need) {
        float*     attn = (float*)ws;
        _Float16*  pT   = (_Float16*)(ws + 67108864);
        _Float16*  W2   = (_Float16*)(ws + 67108864 + 39321600);
        float*     Mp   = (float*)(ws + 139984896);
        float*     Tp   = Mp + (size_t)DEVB * 8 * 512;
        float*     Sp   = Tp + (size_t)DEVB * 8 * 512;
        float*     M1   = Sp + (size_t)DEVB * 8 * 512;
        float*     R1   = M1 + DEVB * LSEQ;
        float*     M2   = R1 + DEVB * LSEQ;
        float*     R2   = M2 + DEVB * LSEQ;

        prep_t<<<DEVB * 80, 256, 0, stream>>>(P, Phi, Plo, pT);
        prep_t<<<DEVB * 80, 256, 0, stream>>>(H, Hhi, nullptr, hT);
        attn_gemm<<<DEVB * 16, 256, 0, stream>>>(Phi, Plo, Hhi, attn);
        // Phi/Plo/Hhi now dead; W1 may overlay Hhi.
        stats_w1<<<DEVB * 8, 256, 0, stream>>>(attn, hm, pm, M1, R1, W1, Mp, Tp, Sp);
        col_merge<<<DEVB * 2, 256, 0, stream>>>(Mp, Tp, Sp, M2, R2);
        w2gen<<<DEVB * 32, 256, 0, stream>>>(attn, pm, M2, R2, W2);
        // gemm<0> reads W1/hT (d_out[78.6:157.3)) while writing out[0:78.6) — disjoint.
        gemm_fp16<<<DEVB * 20, 256, 0, stream>>>(W1, hT, pm, out);
        // gemm<1> reads W2/pT (ws) while writing out[78.6:157.3) (over dead W1/hT).
        gemm_fp16<<<DEVB * 20, 256, 0, stream>>>(W2, pT, hm, out + E);
    } else {
        // fallback: needs attn + partials + stats = 70.78 MB of ws
        float* attn = (float*)ws;
        float* Mp   = (float*)(ws + 67108864);
        float* Tp   = Mp + (size_t)DEVB * 8 * 512;
        float* Sp   = Tp + (size_t)DEVB * 8 * 512;
        float* M1   = Sp + (size_t)DEVB * 8 * 512;
        float* R1   = M1 + DEVB * LSEQ;
        float* M2   = R1 + DEVB * LSEQ;
        float* R2   = M2 + DEVB * LSEQ;

        prep_t<<<DEVB * 80, 256, 0, stream>>>(P, Phi, Plo, nullptr);
        prep_t<<<DEVB * 80, 256, 0, stream>>>(H, Hhi, nullptr, nullptr);
        attn_gemm<<<DEVB * 16, 256, 0, stream>>>(Phi, Plo, Hhi, attn);
        stats_w1<<<DEVB * 8, 256, 0, stream>>>(attn, hm, pm, M1, R1, nullptr, Mp, Tp, Sp);
        col_merge<<<DEVB * 2, 256, 0, stream>>>(Mp, Tp, Sp, M2, R2);
        wsum<0><<<DEVB * 20, 256, 0, stream>>>(attn, H, hm, pm, M1, R1, out);
        wsum<1><<<DEVB * 20, 256, 0, stream>>>(attn, P, pm, hm, M2, R2, out + E);
    }
}